// Round 2
// baseline (417.842 us; speedup 1.0000x reference)
//
#include <hip/hip_runtime.h>

// MHA fused: B=2, S=2048, D=1024, H=16, DK=64.
// Round 8:
//  - Round-7 (64 q-rows/block) REGRESSED: occupancy rose 22->36% but staging
//    doubled (bank conflicts 3.1M->6.3M) and dur went 107->120us. Reverted to
//    128 q-rows/block, 512 blocks.
//  - K/Kl/V LDS staging DELETED: per-head K/V (768 KB) is L2-resident (all 16
//    blocks of a head pin to one XCD via bid&7). Fragments load directly from
//    global/L2; V fragments hoisted to regs before softmax so L2 latency hides
//    under exp VALU work. Guide m169: dropping LDS staging of L2-fit data.
//  - ZERO __syncthreads in the attn loop (sP is per-wave; same-wave lgkmcnt
//    ordering suffices). Waves run fully async -> no lockstep barrier drain.
//  - softmax exp folded: exp2f(x * 0.125*log2e).

constexpr int BB = 2;
constexpr int SS = 2048;
constexpr int DD = 1024;
constexpr int HH = 16;
constexpr int DKK = 64;

typedef float f32x4 __attribute__((ext_vector_type(4)));
typedef __bf16 bf16x8 __attribute__((ext_vector_type(8)));
typedef short s16x8 __attribute__((ext_vector_type(8)));
typedef short s16x4 __attribute__((ext_vector_type(4)));

#define DEV static __device__ __forceinline__

DEV f32x4 mfma16(s16x8 a, s16x8 b, f32x4 c) {
  return __builtin_amdgcn_mfma_f32_16x16x32_bf16(
      __builtin_bit_cast(bf16x8, a), __builtin_bit_cast(bf16x8, b), c, 0, 0, 0);
}

DEV void split1(float x, short& h, short& l) {  // x ~= hi + lo (both bf16)
  unsigned u = __float_as_uint(x);
  h = (short)(u >> 16);
  float hf = __uint_as_float(u & 0xffff0000u);
  l = (short)(__float_as_uint(x - hf) >> 16);
}
DEV short f2bf_rne(float x) {  // round-to-nearest-even bf16
  unsigned u = __float_as_uint(x);
  return (short)((u + 0x7fffu + ((u >> 16) & 1u)) >> 16);
}
DEV s16x8 load8s(const short* p) { return *(const s16x8*)p; }

DEV void gld_lds16(const short* g, short* l) {
  __builtin_amdgcn_global_load_lds(
      (const __attribute__((address_space(1))) void*)g,
      (__attribute__((address_space(3))) void*)l, 16, 0, 0);
}

// ---------------------------------------------------------------- elementwise
__global__ __launch_bounds__(256) void split_pair(const float* __restrict__ X,
                                                  short* __restrict__ H,
                                                  short* __restrict__ L) {
  int i = (blockIdx.x * 256 + threadIdx.x) * 4;
  float4 x = *(const float4*)(X + i);
  float xs[4] = {x.x, x.y, x.z, x.w};
  s16x4 h4, l4;
#pragma unroll
  for (int e = 0; e < 4; ++e) {
    short h, l;
    split1(xs[e], h, l);
    h4[e] = h;
    l4[e] = l;
  }
  *(s16x4*)(H + i) = h4;
  *(s16x4*)(L + i) = l4;
}

__global__ __launch_bounds__(256) void cast_rne(const float* __restrict__ X,
                                                short* __restrict__ Y) {
  int i = (blockIdx.x * 256 + threadIdx.x) * 4;
  float4 x = *(const float4*)(X + i);
  float xs[4] = {x.x, x.y, x.z, x.w};
  s16x4 y4;
#pragma unroll
  for (int e = 0; e < 4; ++e) y4[e] = f2bf_rne(xs[e]);
  *(s16x4*)(Y + i) = y4;
}

// ---------------------------------------------------------------- merged Q+K projection
// Grid 1024: blocks 0-511 compute Q tiles (plain bf16 out, [B,H,S,DK]),
// blocks 512-1023 compute K tiles (hi/lo bf16 out, [B,H,S,DK]).
// Tile 128(M) x 64(N), BK=32, LDS double-buffered split K-loop.
__global__ __launch_bounds__(256) void gemm_qk(
    const short* __restrict__ qAh, const short* __restrict__ qAl,
    const short* __restrict__ Wqh, const short* __restrict__ Wql,
    const float* __restrict__ bq, short* __restrict__ Qo,
    const short* __restrict__ kAh, const short* __restrict__ kAl,
    const short* __restrict__ Wkh, const short* __restrict__ Wkl,
    const float* __restrict__ bk, short* __restrict__ Kho,
    short* __restrict__ Klo) {
  __shared__ short lds[2][12288];

  const int tid = threadIdx.x;
  const int lane = tid & 63, wv = tid >> 6;
  const int lo16 = lane & 15, quad = lane >> 4;
  const int sel = blockIdx.x >> 9;  // 0 = Q, 1 = K
  const int bid = blockIdx.x & 511;
  const int m0 = (bid & 31) * 128;
  const int n0 = (bid >> 5) * 64;

  const short* Agh = sel ? kAh : qAh;
  const short* Agl = sel ? kAl : qAl;
  const short* Wgh = sel ? Wkh : Wqh;
  const short* Wgl = sel ? Wkl : Wql;
  const float* bias = sel ? bk : bq;

  f32x4 acc[2][4];
#pragma unroll
  for (int mt = 0; mt < 2; ++mt)
#pragma unroll
    for (int nt = 0; nt < 4; ++nt) acc[mt][nt] = f32x4{0.f, 0.f, 0.f, 0.f};

  const int rw = tid >> 2, qw = tid & 3;
  const int ra0 = tid >> 2, ra1 = (tid + 256) >> 2;

  auto stage = [&](int k0, int buf) {
    short* sAh = lds[buf];
    short* sAl = lds[buf] + 4096;
    short* sWh = lds[buf] + 8192;
    short* sWl = lds[buf] + 10240;
    gld_lds16(Wgh + (size_t)(n0 + rw) * DD + k0 + qw * 8, sWh + tid * 8);
    gld_lds16(Wgl + (size_t)(n0 + rw) * DD + k0 + qw * 8, sWl + tid * 8);
    gld_lds16(Agh + (size_t)(m0 + ra0) * DD + k0 + qw * 8, sAh + tid * 8);
    gld_lds16(Agh + (size_t)(m0 + ra1) * DD + k0 + qw * 8, sAh + (tid + 256) * 8);
    gld_lds16(Agl + (size_t)(m0 + ra0) * DD + k0 + qw * 8, sAl + tid * 8);
    gld_lds16(Agl + (size_t)(m0 + ra1) * DD + k0 + qw * 8, sAl + (tid + 256) * 8);
  };

  stage(0, 0);

  for (int kk = 0; kk < DD / 32; ++kk) {
    __syncthreads();
    if (kk + 1 < DD / 32) stage((kk + 1) * 32, (kk + 1) & 1);

    const short* sAh = lds[kk & 1];
    const short* sAl = lds[kk & 1] + 4096;
    const short* sWh = lds[kk & 1] + 8192;
    const short* sWl = lds[kk & 1] + 10240;

    s16x8 ah[2], al[2], wh[4], wl[4];
#pragma unroll
    for (int mt = 0; mt < 2; ++mt) {
      const int r = wv * 32 + mt * 16 + lo16;
      ah[mt] = *(const s16x8*)&sAh[r * 32 + quad * 8];
      al[mt] = *(const s16x8*)&sAl[r * 32 + quad * 8];
    }
#pragma unroll
    for (int nt = 0; nt < 4; ++nt) {
      const int r = nt * 16 + lo16;
      wh[nt] = *(const s16x8*)&sWh[r * 32 + quad * 8];
      wl[nt] = *(const s16x8*)&sWl[r * 32 + quad * 8];
    }
#pragma unroll
    for (int mt = 0; mt < 2; ++mt)
#pragma unroll
      for (int nt = 0; nt < 4; ++nt) {
        acc[mt][nt] = mfma16(ah[mt], wh[nt], acc[mt][nt]);
        acc[mt][nt] = mfma16(ah[mt], wl[nt], acc[mt][nt]);
        acc[mt][nt] = mfma16(al[mt], wh[nt], acc[mt][nt]);
      }
  }

#pragma unroll
  for (int mt = 0; mt < 2; ++mt)
#pragma unroll
    for (int nt = 0; nt < 4; ++nt) {
      const int n = n0 + nt * 16 + lo16;
      const float bv = bias[n];
#pragma unroll
      for (int r = 0; r < 4; ++r) {
        const int m = m0 + wv * 32 + mt * 16 + quad * 4 + r;
        const float val = acc[mt][nt][r] + bv;
        const int b = m >> 11, s = m & 2047;
        const int h = n >> 6, dk = n & 63;
        size_t idx = ((size_t)(b * HH + h) * SS + s) * DKK + dk;
        if (sel == 0) {
          Qo[idx] = f2bf_rne(val);
        } else {
          short hh, ll;
          split1(val, hh, ll);
          Kho[idx] = hh;
          Klo[idx] = ll;
        }
      }
    }
}

// ---------------------------------------------------------------- GEMM C = A @ W^T + b
// EPI 1: plain A/W, out bf16 -> [B,H,DK,S] (V transposed)
// EPI 2: split A/W, out fp32 -> [4096,1024] (final output)
template <int SPLIT, int EPI>
__global__ __launch_bounds__(256) void gemm_tile(
    const short* __restrict__ Agh, const short* __restrict__ Agl,
    const short* __restrict__ Wgh, const short* __restrict__ Wgl,
    const float* __restrict__ bias, void* __restrict__ O1, void* __restrict__ O2) {
  __shared__ short lds[2][12288];

  const int tid = threadIdx.x;
  const int lane = tid & 63, wv = tid >> 6;
  const int lo16 = lane & 15, quad = lane >> 4;
  const int m0 = (blockIdx.x & 31) * 128;
  const int n0 = (blockIdx.x >> 5) * 64;

  f32x4 acc[2][4];
#pragma unroll
  for (int mt = 0; mt < 2; ++mt)
#pragma unroll
    for (int nt = 0; nt < 4; ++nt) acc[mt][nt] = f32x4{0.f, 0.f, 0.f, 0.f};

  const int rw = tid >> 2, qw = tid & 3;
  const int ra0 = tid >> 2, ra1 = (tid + 256) >> 2;

  auto stage = [&](int k0, int buf) {
    short* sAh = lds[buf];
    short* sAl = lds[buf] + 4096;
    short* sWh = lds[buf] + 8192;
    short* sWl = lds[buf] + 10240;
    gld_lds16(Wgh + (size_t)(n0 + rw) * DD + k0 + qw * 8, sWh + tid * 8);
    if constexpr (SPLIT)
      gld_lds16(Wgl + (size_t)(n0 + rw) * DD + k0 + qw * 8, sWl + tid * 8);
    gld_lds16(Agh + (size_t)(m0 + ra0) * DD + k0 + qw * 8, sAh + tid * 8);
    gld_lds16(Agh + (size_t)(m0 + ra1) * DD + k0 + qw * 8, sAh + (tid + 256) * 8);
    if constexpr (SPLIT) {
      gld_lds16(Agl + (size_t)(m0 + ra0) * DD + k0 + qw * 8, sAl + tid * 8);
      gld_lds16(Agl + (size_t)(m0 + ra1) * DD + k0 + qw * 8, sAl + (tid + 256) * 8);
    }
  };

  stage(0, 0);

  for (int kk = 0; kk < DD / 32; ++kk) {
    __syncthreads();
    if (kk + 1 < DD / 32) stage((kk + 1) * 32, (kk + 1) & 1);

    const short* sAh = lds[kk & 1];
    const short* sAl = lds[kk & 1] + 4096;
    const short* sWh = lds[kk & 1] + 8192;
    const short* sWl = lds[kk & 1] + 10240;

    s16x8 ah[2], al[2], wh[4], wl[4];
#pragma unroll
    for (int mt = 0; mt < 2; ++mt) {
      const int r = wv * 32 + mt * 16 + lo16;
      ah[mt] = *(const s16x8*)&sAh[r * 32 + quad * 8];
      if constexpr (SPLIT) al[mt] = *(const s16x8*)&sAl[r * 32 + quad * 8];
    }
#pragma unroll
    for (int nt = 0; nt < 4; ++nt) {
      const int r = nt * 16 + lo16;
      wh[nt] = *(const s16x8*)&sWh[r * 32 + quad * 8];
      if constexpr (SPLIT) wl[nt] = *(const s16x8*)&sWl[r * 32 + quad * 8];
    }
#pragma unroll
    for (int mt = 0; mt < 2; ++mt)
#pragma unroll
      for (int nt = 0; nt < 4; ++nt) {
        acc[mt][nt] = mfma16(ah[mt], wh[nt], acc[mt][nt]);
        if constexpr (SPLIT) {
          acc[mt][nt] = mfma16(ah[mt], wl[nt], acc[mt][nt]);
          acc[mt][nt] = mfma16(al[mt], wh[nt], acc[mt][nt]);
        }
      }
  }

#pragma unroll
  for (int mt = 0; mt < 2; ++mt)
#pragma unroll
    for (int nt = 0; nt < 4; ++nt) {
      const int n = n0 + nt * 16 + lo16;
      const float bv = bias[n];
#pragma unroll
      for (int r = 0; r < 4; ++r) {
        const int m = m0 + wv * 32 + mt * 16 + quad * 4 + r;
        const float val = acc[mt][nt][r] + bv;
        const int b = m >> 11, s = m & 2047;
        const int h = n >> 6, dk = n & 63;
        if constexpr (EPI == 1) {
          size_t idx = ((size_t)(b * HH + h) * DKK + dk) * SS + s;
          ((short*)O1)[idx] = f2bf_rne(val);
        } else {
          ((float*)O1)[(size_t)m * DD + n] = val;
        }
      }
    }
}

// ---------------------------------------------------------------- flash attention
// Block = 128 q-rows of one head (4 waves x 32 rows), grid 512.
// NO K/V LDS staging: fragments load directly from L2 (per-head K/Kl/V=768KB,
// 16 blocks/head pinned to one XCD's 4MB L2 via bid&7). No __syncthreads at
// all: sP is per-wave, lgkmcnt handles same-wave write->read ordering.
// No-max softmax. Q plain bf16; K hi/lo (2-term QK MFMA).
constexpr int PAD = 68;
constexpr int NKB = SS / 64;  // 32
constexpr float EXPSC = 0.125f * 1.4426950408889634f;  // fold /sqrt(DK) into exp2

__global__ __launch_bounds__(256, 2) void mha_attn(
    const short* __restrict__ Qh, const short* __restrict__ Kh,
    const short* __restrict__ Kl, const short* __restrict__ Vt,
    const int* __restrict__ mask, short* __restrict__ Ah,
    short* __restrict__ Al) {
  __shared__ short sP[4][32 * PAD];

  const int tid = threadIdx.x;
  const int lane = tid & 63, wv = tid >> 6;
  const int lo16 = lane & 15, quad = lane >> 4;
  const int bid = blockIdx.x;                         // 512 blocks
  const int head = (bid & 7) * 4 + ((bid >> 3) & 3);  // = b*16 + h (head->XCD pin)
  const int qblk = bid >> 5;                          // 0..15
  const int q0 = qblk * 128 + wv * 32;                // this wave's 32 q rows
  const int b = head >> 4;

  const size_t hbase = (size_t)head * SS;

  s16x8 qh[2][2];
#pragma unroll
  for (int rt = 0; rt < 2; ++rt) {
    size_t qb = (hbase + q0 + rt * 16 + lo16) * DKK + quad * 8;
#pragma unroll
    for (int c = 0; c < 2; ++c) qh[rt][c] = load8s(Qh + qb + c * 32);
  }

  f32x4 Oacc[2][4];
#pragma unroll
  for (int rt = 0; rt < 2; ++rt)
#pragma unroll
    for (int t = 0; t < 4; ++t) Oacc[rt][t] = f32x4{0.f, 0.f, 0.f, 0.f};
  float lsum[2][4];
#pragma unroll
  for (int rt = 0; rt < 2; ++rt)
#pragma unroll
    for (int r = 0; r < 4; ++r) lsum[rt][r] = 0.f;

  for (int kb = 0; kb < NKB; ++kb) {
    const int k0g = kb * 64;

    // ---- QK^T: K fragments straight from L2
    f32x4 sc4[2][4];
    int mv[4];
#pragma unroll
    for (int sub = 0; sub < 4; ++sub) {
      mv[sub] = mask[b * SS + k0g + sub * 16 + lo16];
      sc4[0][sub] = f32x4{0.f, 0.f, 0.f, 0.f};
      sc4[1][sub] = f32x4{0.f, 0.f, 0.f, 0.f};
      const size_t krow = hbase + k0g + sub * 16 + lo16;
#pragma unroll
      for (int c = 0; c < 2; ++c) {
        s16x8 kh = load8s(Kh + krow * DKK + c * 32 + quad * 8);
        s16x8 kl = load8s(Kl + krow * DKK + c * 32 + quad * 8);
#pragma unroll
        for (int rt = 0; rt < 2; ++rt) {
          sc4[rt][sub] = mfma16(qh[rt][c], kh, sc4[rt][sub]);
          sc4[rt][sub] = mfma16(qh[rt][c], kl, sc4[rt][sub]);
        }
      }
    }

    // ---- V fragments: issue loads now so L2 latency hides under softmax VALU
    s16x8 vbr[4][2];
#pragma unroll
    for (int t = 0; t < 4; ++t)
#pragma unroll
      for (int c = 0; c < 2; ++c)
        vbr[t][c] = load8s(Vt + ((size_t)head * DKK + t * 16 + lo16) * SS +
                           k0g + c * 32 + quad * 8);

    // ---- softmax (no-max): p = exp2(s * 0.125*log2e), masked
#pragma unroll
    for (int rt = 0; rt < 2; ++rt)
#pragma unroll
      for (int sub = 0; sub < 4; ++sub)
#pragma unroll
        for (int r = 0; r < 4; ++r) {
          float p = exp2f(sc4[rt][sub][r] * EXPSC);
          p = mv[sub] ? p : 0.f;
          lsum[rt][r] += p;
          sP[wv][(rt * 16 + quad * 4 + r) * PAD + sub * 16 + lo16] = f2bf_rne(p);
        }

    // ---- PV
    s16x8 pa[2][2];
#pragma unroll
    for (int rt = 0; rt < 2; ++rt)
#pragma unroll
      for (int c = 0; c < 2; ++c)
        pa[rt][c] = *(const s16x8*)&sP[wv][(rt * 16 + lo16) * PAD + c * 32 + quad * 8];
#pragma unroll
    for (int t = 0; t < 4; ++t)
#pragma unroll
      for (int c = 0; c < 2; ++c) {
#pragma unroll
        for (int rt = 0; rt < 2; ++rt)
          Oacc[rt][t] = mfma16(pa[rt][c], vbr[t][c], Oacc[rt][t]);
      }
    // no barrier: waves fully independent
  }

  const int h = head & 15;
#pragma unroll
  for (int rt = 0; rt < 2; ++rt)
#pragma unroll
    for (int r = 0; r < 4; ++r) {
      float s = lsum[rt][r];
#pragma unroll
      for (int off = 1; off < 16; off <<= 1) s += __shfl_xor(s, off);
      const float rinv = 1.0f / s;
#pragma unroll
      for (int t = 0; t < 4; ++t) {
        const float val = Oacc[rt][t][r] * rinv;
        const int row = q0 + rt * 16 + quad * 4 + r;
        const int col = h * DKK + t * 16 + lo16;
        const size_t idx = ((size_t)b * SS + row) * DD + col;
        short hh, ll;
        split1(val, hh, ll);
        Ah[idx] = hh;
        Al[idx] = ll;
      }
    }
}

// ---------------------------------------------------------------- launch
extern "C" void kernel_launch(void* const* d_in, const int* in_sizes, int n_in,
                              void* d_out, int out_size, void* d_ws, size_t ws_size,
                              hipStream_t stream) {
  const float* q = (const float*)d_in[0];
  const float* k = (const float*)d_in[1];
  const float* v = (const float*)d_in[2];
  const int* mask = (const int*)d_in[3];
  const float* Wq = (const float*)d_in[4];
  const float* bq = (const float*)d_in[5];
  const float* Wk = (const float*)d_in[6];
  const float* bk = (const float*)d_in[7];
  const float* Wv = (const float*)d_in[8];
  const float* bv = (const float*)d_in[9];
  const float* Wo = (const float*)d_in[10];
  const float* bo = (const float*)d_in[11];

  char* ws = (char*)d_ws;
  size_t off = 0;
  auto take = [&](size_t bytes) {
    char* p = ws + off;
    off += (bytes + 255) & ~(size_t)255;
    return p;
  };
  const size_t WE = (size_t)DD * DD;       // 1,048,576
  const size_t TE = (size_t)BB * SS * DD;  // 4,194,304

  short* Wqh = (short*)take(WE * 2);
  short* Wql = (short*)take(WE * 2);
  short* Wkh = (short*)take(WE * 2);
  short* Wkl = (short*)take(WE * 2);
  short* Wvh = (short*)take(WE * 2);
  short* Woh = (short*)take(WE * 2);
  short* Wol = (short*)take(WE * 2);
  short* qH = (short*)take(TE * 2);
  short* qL = (short*)take(TE * 2);
  short* kH = (short*)take(TE * 2);
  short* kL = (short*)take(TE * 2);
  short* Qh = (short*)take(TE * 2);
  short* Kh = (short*)take(TE * 2);
  short* Kl = (short*)take(TE * 2);
  (void)ws_size;  // 70 MB peak (aliased below)
  // aliases (lifetimes disjoint on the serial stream):
  short* vH = qH;  // v cast, after gemm_qk consumed qH
  short* Vt = qL;  // V-proj out, after gemm_qk consumed qL
  short* aH = kH;  // attn out hi, after gemm_qk consumed kH
  short* aL = kL;  // attn out lo

  // weights
  split_pair<<<1024, 256, 0, stream>>>(Wq, Wqh, Wql);
  split_pair<<<1024, 256, 0, stream>>>(Wk, Wkh, Wkl);
  split_pair<<<1024, 256, 0, stream>>>(Wo, Woh, Wol);
  cast_rne<<<1024, 256, 0, stream>>>(Wv, Wvh);

  // activation splits
  split_pair<<<4096, 256, 0, stream>>>(q, qH, qL);
  split_pair<<<4096, 256, 0, stream>>>(k, kH, kL);

  // merged Q+K projection (1024 blocks -> 3 blocks/CU)
  gemm_qk<<<1024, 256, 0, stream>>>(qH, qL, Wqh, Wql, bq, Qh,
                                    kH, kL, Wkh, Wkl, bk, Kh, Kl);

  // V projection (plain bf16, transposed output)
  cast_rne<<<4096, 256, 0, stream>>>(v, vH);
  gemm_tile<0, 1><<<512, 256, 0, stream>>>(vH, nullptr, Wvh, nullptr, bv, Vt, nullptr);

  // attention (barrier-free, direct-L2 K/V)
  mha_attn<<<512, 256, 0, stream>>>(Qh, Kh, Kl, Vt, mask, aH, aL);

  // output projection
  gemm_tile<1, 2><<<512, 256, 0, stream>>>(aH, aL, Woh, Wol, bo, d_out, nullptr);
}

// Round 3
// 338.892 us; speedup vs baseline: 1.2330x; 1.2330x over previous
//
#include <hip/hip_runtime.h>

// MHA fused: B=2, S=2048, D=1024, H=16, DK=64.
// Round 9:
//  - Round-8 (no LDS staging) REGRESSED hard (107->188us): direct-L2 K/V put
//    ~200cy vmcnt waits on every MFMA chain at only 8 waves/CU. Staging's
//    register-prefetch structure was real latency hiding. Reverted.
//  - This round: same staged structure as round 6, but 512-THREAD BLOCKS
//    (8 waves x 16 q-rows = 128 q-rows/block, grid 512). Chip-wide staging
//    traffic identical to round 6; waves amortizing each staged tile double;
//    LDS stays 43520 B -> 3 blocks/CU, 24 waves/CU (vs round 6's 8).
//  - softmax exp folded: exp2f(x * 0.125*log2e).

constexpr int BB = 2;
constexpr int SS = 2048;
constexpr int DD = 1024;
constexpr int HH = 16;
constexpr int DKK = 64;

typedef float f32x4 __attribute__((ext_vector_type(4)));
typedef __bf16 bf16x8 __attribute__((ext_vector_type(8)));
typedef short s16x8 __attribute__((ext_vector_type(8)));
typedef short s16x4 __attribute__((ext_vector_type(4)));

#define DEV static __device__ __forceinline__

DEV f32x4 mfma16(s16x8 a, s16x8 b, f32x4 c) {
  return __builtin_amdgcn_mfma_f32_16x16x32_bf16(
      __builtin_bit_cast(bf16x8, a), __builtin_bit_cast(bf16x8, b), c, 0, 0, 0);
}

DEV void split1(float x, short& h, short& l) {  // x ~= hi + lo (both bf16)
  unsigned u = __float_as_uint(x);
  h = (short)(u >> 16);
  float hf = __uint_as_float(u & 0xffff0000u);
  l = (short)(__float_as_uint(x - hf) >> 16);
}
DEV short f2bf_rne(float x) {  // round-to-nearest-even bf16
  unsigned u = __float_as_uint(x);
  return (short)((u + 0x7fffu + ((u >> 16) & 1u)) >> 16);
}
DEV s16x8 load8s(const short* p) { return *(const s16x8*)p; }

DEV void gld_lds16(const short* g, short* l) {
  __builtin_amdgcn_global_load_lds(
      (const __attribute__((address_space(1))) void*)g,
      (__attribute__((address_space(3))) void*)l, 16, 0, 0);
}

// ---------------------------------------------------------------- elementwise
__global__ __launch_bounds__(256) void split_pair(const float* __restrict__ X,
                                                  short* __restrict__ H,
                                                  short* __restrict__ L) {
  int i = (blockIdx.x * 256 + threadIdx.x) * 4;
  float4 x = *(const float4*)(X + i);
  float xs[4] = {x.x, x.y, x.z, x.w};
  s16x4 h4, l4;
#pragma unroll
  for (int e = 0; e < 4; ++e) {
    short h, l;
    split1(xs[e], h, l);
    h4[e] = h;
    l4[e] = l;
  }
  *(s16x4*)(H + i) = h4;
  *(s16x4*)(L + i) = l4;
}

__global__ __launch_bounds__(256) void cast_rne(const float* __restrict__ X,
                                                short* __restrict__ Y) {
  int i = (blockIdx.x * 256 + threadIdx.x) * 4;
  float4 x = *(const float4*)(X + i);
  float xs[4] = {x.x, x.y, x.z, x.w};
  s16x4 y4;
#pragma unroll
  for (int e = 0; e < 4; ++e) y4[e] = f2bf_rne(xs[e]);
  *(s16x4*)(Y + i) = y4;
}

// ---------------------------------------------------------------- merged Q+K projection
// Grid 1024: blocks 0-511 compute Q tiles (plain bf16 out, [B,H,S,DK]),
// blocks 512-1023 compute K tiles (hi/lo bf16 out, [B,H,S,DK]).
// Tile 128(M) x 64(N), BK=32, LDS double-buffered split K-loop.
__global__ __launch_bounds__(256) void gemm_qk(
    const short* __restrict__ qAh, const short* __restrict__ qAl,
    const short* __restrict__ Wqh, const short* __restrict__ Wql,
    const float* __restrict__ bq, short* __restrict__ Qo,
    const short* __restrict__ kAh, const short* __restrict__ kAl,
    const short* __restrict__ Wkh, const short* __restrict__ Wkl,
    const float* __restrict__ bk, short* __restrict__ Kho,
    short* __restrict__ Klo) {
  __shared__ short lds[2][12288];

  const int tid = threadIdx.x;
  const int lane = tid & 63, wv = tid >> 6;
  const int lo16 = lane & 15, quad = lane >> 4;
  const int sel = blockIdx.x >> 9;  // 0 = Q, 1 = K
  const int bid = blockIdx.x & 511;
  const int m0 = (bid & 31) * 128;
  const int n0 = (bid >> 5) * 64;

  const short* Agh = sel ? kAh : qAh;
  const short* Agl = sel ? kAl : qAl;
  const short* Wgh = sel ? Wkh : Wqh;
  const short* Wgl = sel ? Wkl : Wql;
  const float* bias = sel ? bk : bq;

  f32x4 acc[2][4];
#pragma unroll
  for (int mt = 0; mt < 2; ++mt)
#pragma unroll
    for (int nt = 0; nt < 4; ++nt) acc[mt][nt] = f32x4{0.f, 0.f, 0.f, 0.f};

  const int rw = tid >> 2, qw = tid & 3;
  const int ra0 = tid >> 2, ra1 = (tid + 256) >> 2;

  auto stage = [&](int k0, int buf) {
    short* sAh = lds[buf];
    short* sAl = lds[buf] + 4096;
    short* sWh = lds[buf] + 8192;
    short* sWl = lds[buf] + 10240;
    gld_lds16(Wgh + (size_t)(n0 + rw) * DD + k0 + qw * 8, sWh + tid * 8);
    gld_lds16(Wgl + (size_t)(n0 + rw) * DD + k0 + qw * 8, sWl + tid * 8);
    gld_lds16(Agh + (size_t)(m0 + ra0) * DD + k0 + qw * 8, sAh + tid * 8);
    gld_lds16(Agh + (size_t)(m0 + ra1) * DD + k0 + qw * 8, sAh + (tid + 256) * 8);
    gld_lds16(Agl + (size_t)(m0 + ra0) * DD + k0 + qw * 8, sAl + tid * 8);
    gld_lds16(Agl + (size_t)(m0 + ra1) * DD + k0 + qw * 8, sAl + (tid + 256) * 8);
  };

  stage(0, 0);

  for (int kk = 0; kk < DD / 32; ++kk) {
    __syncthreads();
    if (kk + 1 < DD / 32) stage((kk + 1) * 32, (kk + 1) & 1);

    const short* sAh = lds[kk & 1];
    const short* sAl = lds[kk & 1] + 4096;
    const short* sWh = lds[kk & 1] + 8192;
    const short* sWl = lds[kk & 1] + 10240;

    s16x8 ah[2], al[2], wh[4], wl[4];
#pragma unroll
    for (int mt = 0; mt < 2; ++mt) {
      const int r = wv * 32 + mt * 16 + lo16;
      ah[mt] = *(const s16x8*)&sAh[r * 32 + quad * 8];
      al[mt] = *(const s16x8*)&sAl[r * 32 + quad * 8];
    }
#pragma unroll
    for (int nt = 0; nt < 4; ++nt) {
      const int r = nt * 16 + lo16;
      wh[nt] = *(const s16x8*)&sWh[r * 32 + quad * 8];
      wl[nt] = *(const s16x8*)&sWl[r * 32 + quad * 8];
    }
#pragma unroll
    for (int mt = 0; mt < 2; ++mt)
#pragma unroll
      for (int nt = 0; nt < 4; ++nt) {
        acc[mt][nt] = mfma16(ah[mt], wh[nt], acc[mt][nt]);
        acc[mt][nt] = mfma16(ah[mt], wl[nt], acc[mt][nt]);
        acc[mt][nt] = mfma16(al[mt], wh[nt], acc[mt][nt]);
      }
  }

#pragma unroll
  for (int mt = 0; mt < 2; ++mt)
#pragma unroll
    for (int nt = 0; nt < 4; ++nt) {
      const int n = n0 + nt * 16 + lo16;
      const float bv = bias[n];
#pragma unroll
      for (int r = 0; r < 4; ++r) {
        const int m = m0 + wv * 32 + mt * 16 + quad * 4 + r;
        const float val = acc[mt][nt][r] + bv;
        const int b = m >> 11, s = m & 2047;
        const int h = n >> 6, dk = n & 63;
        size_t idx = ((size_t)(b * HH + h) * SS + s) * DKK + dk;
        if (sel == 0) {
          Qo[idx] = f2bf_rne(val);
        } else {
          short hh, ll;
          split1(val, hh, ll);
          Kho[idx] = hh;
          Klo[idx] = ll;
        }
      }
    }
}

// ---------------------------------------------------------------- GEMM C = A @ W^T + b
// EPI 1: plain A/W, out bf16 -> [B,H,DK,S] (V transposed)
// EPI 2: split A/W, out fp32 -> [4096,1024] (final output)
template <int SPLIT, int EPI>
__global__ __launch_bounds__(256) void gemm_tile(
    const short* __restrict__ Agh, const short* __restrict__ Agl,
    const short* __restrict__ Wgh, const short* __restrict__ Wgl,
    const float* __restrict__ bias, void* __restrict__ O1, void* __restrict__ O2) {
  __shared__ short lds[2][12288];

  const int tid = threadIdx.x;
  const int lane = tid & 63, wv = tid >> 6;
  const int lo16 = lane & 15, quad = lane >> 4;
  const int m0 = (blockIdx.x & 31) * 128;
  const int n0 = (blockIdx.x >> 5) * 64;

  f32x4 acc[2][4];
#pragma unroll
  for (int mt = 0; mt < 2; ++mt)
#pragma unroll
    for (int nt = 0; nt < 4; ++nt) acc[mt][nt] = f32x4{0.f, 0.f, 0.f, 0.f};

  const int rw = tid >> 2, qw = tid & 3;
  const int ra0 = tid >> 2, ra1 = (tid + 256) >> 2;

  auto stage = [&](int k0, int buf) {
    short* sAh = lds[buf];
    short* sAl = lds[buf] + 4096;
    short* sWh = lds[buf] + 8192;
    short* sWl = lds[buf] + 10240;
    gld_lds16(Wgh + (size_t)(n0 + rw) * DD + k0 + qw * 8, sWh + tid * 8);
    if constexpr (SPLIT)
      gld_lds16(Wgl + (size_t)(n0 + rw) * DD + k0 + qw * 8, sWl + tid * 8);
    gld_lds16(Agh + (size_t)(m0 + ra0) * DD + k0 + qw * 8, sAh + tid * 8);
    gld_lds16(Agh + (size_t)(m0 + ra1) * DD + k0 + qw * 8, sAh + (tid + 256) * 8);
    if constexpr (SPLIT) {
      gld_lds16(Agl + (size_t)(m0 + ra0) * DD + k0 + qw * 8, sAl + tid * 8);
      gld_lds16(Agl + (size_t)(m0 + ra1) * DD + k0 + qw * 8, sAl + (tid + 256) * 8);
    }
  };

  stage(0, 0);

  for (int kk = 0; kk < DD / 32; ++kk) {
    __syncthreads();
    if (kk + 1 < DD / 32) stage((kk + 1) * 32, (kk + 1) & 1);

    const short* sAh = lds[kk & 1];
    const short* sAl = lds[kk & 1] + 4096;
    const short* sWh = lds[kk & 1] + 8192;
    const short* sWl = lds[kk & 1] + 10240;

    s16x8 ah[2], al[2], wh[4], wl[4];
#pragma unroll
    for (int mt = 0; mt < 2; ++mt) {
      const int r = wv * 32 + mt * 16 + lo16;
      ah[mt] = *(const s16x8*)&sAh[r * 32 + quad * 8];
      if constexpr (SPLIT) al[mt] = *(const s16x8*)&sAl[r * 32 + quad * 8];
    }
#pragma unroll
    for (int nt = 0; nt < 4; ++nt) {
      const int r = nt * 16 + lo16;
      wh[nt] = *(const s16x8*)&sWh[r * 32 + quad * 8];
      if constexpr (SPLIT) wl[nt] = *(const s16x8*)&sWl[r * 32 + quad * 8];
    }
#pragma unroll
    for (int mt = 0; mt < 2; ++mt)
#pragma unroll
      for (int nt = 0; nt < 4; ++nt) {
        acc[mt][nt] = mfma16(ah[mt], wh[nt], acc[mt][nt]);
        if constexpr (SPLIT) {
          acc[mt][nt] = mfma16(ah[mt], wl[nt], acc[mt][nt]);
          acc[mt][nt] = mfma16(al[mt], wh[nt], acc[mt][nt]);
        }
      }
  }

#pragma unroll
  for (int mt = 0; mt < 2; ++mt)
#pragma unroll
    for (int nt = 0; nt < 4; ++nt) {
      const int n = n0 + nt * 16 + lo16;
      const float bv = bias[n];
#pragma unroll
      for (int r = 0; r < 4; ++r) {
        const int m = m0 + wv * 32 + mt * 16 + quad * 4 + r;
        const float val = acc[mt][nt][r] + bv;
        const int b = m >> 11, s = m & 2047;
        const int h = n >> 6, dk = n & 63;
        if constexpr (EPI == 1) {
          size_t idx = ((size_t)(b * HH + h) * DKK + dk) * SS + s;
          ((short*)O1)[idx] = f2bf_rne(val);
        } else {
          ((float*)O1)[(size_t)m * DD + n] = val;
        }
      }
    }
}

// ---------------------------------------------------------------- flash attention
// Block = 128 q-rows of one head, 512 THREADS (8 waves x 16 q-rows), grid 512.
// K/Kl/V staged in LDS per 64-key iteration (same chip-wide staging traffic as
// round 6) but amortized over 8 waves; next tile register-prefetched.
// LDS = 3*64*PAD*2 + 8*16*PAD*2 = 43520 B -> 3 blocks/CU = 24 waves/CU.
// No-max softmax. Q plain bf16; K hi/lo (2-term QK MFMA).
constexpr int PAD = 68;
constexpr int NKB = SS / 64;  // 32
constexpr float EXPSC = 0.125f * 1.4426950408889634f;  // fold /sqrt(DK) into exp2

__global__ __launch_bounds__(512, 6) void mha_attn(
    const short* __restrict__ Qh, const short* __restrict__ Kh,
    const short* __restrict__ Kl, const short* __restrict__ Vt,
    const int* __restrict__ mask, short* __restrict__ Ah,
    short* __restrict__ Al) {
  __shared__ short sKh[64 * PAD];
  __shared__ short sKl[64 * PAD];
  __shared__ short sV[64 * PAD];
  __shared__ short sP[8][16 * PAD];

  const int tid = threadIdx.x;
  const int lane = tid & 63, wv = tid >> 6;  // wv 0..7
  const int lo16 = lane & 15, quad = lane >> 4;
  const int bid = blockIdx.x;                         // 512 blocks
  const int head = (bid & 7) * 4 + ((bid >> 3) & 3);  // = b*16 + h (head->XCD pin)
  const int qblk = bid >> 5;                          // 0..15
  const int q0 = qblk * 128 + wv * 16;                // this wave's 16 q rows
  const int b = head >> 4;

  const size_t hbase = (size_t)head * SS;

  s16x8 qh[2];
  {
    size_t qb = (hbase + q0 + lo16) * DKK + quad * 8;
    qh[0] = load8s(Qh + qb);
    qh[1] = load8s(Qh + qb + 32);
  }

  f32x4 Oacc[4];
#pragma unroll
  for (int t = 0; t < 4; ++t) Oacc[t] = f32x4{0.f, 0.f, 0.f, 0.f};
  float lsum[4] = {0.f, 0.f, 0.f, 0.f};

  // staging decomposition for 512 threads: 1x 16B chunk per buffer per thread
  const int srow = tid >> 3;            // 0..63
  const int scol = (tid & 7) * 8;       // 0..56

  s16x8 rKh, rKl, rV;
  rKh = load8s(Kh + (hbase + srow) * DKK + scol);
  rKl = load8s(Kl + (hbase + srow) * DKK + scol);
  rV = load8s(Vt + ((size_t)head * DKK + srow) * SS + scol);

  for (int kb = 0; kb < NKB; ++kb) {
    const int k0g = kb * 64;
    *(s16x8*)&sKh[srow * PAD + scol] = rKh;
    *(s16x8*)&sKl[srow * PAD + scol] = rKl;
    *(s16x8*)&sV[srow * PAD + scol] = rV;
    __syncthreads();

    if (kb + 1 < NKB) {
      const int k0n = k0g + 64;
      rKh = load8s(Kh + (hbase + k0n + srow) * DKK + scol);
      rKl = load8s(Kl + (hbase + k0n + srow) * DKK + scol);
      rV = load8s(Vt + ((size_t)head * DKK + srow) * SS + k0n + scol);
    }

    f32x4 sc4[4];
    int mv[4];
#pragma unroll
    for (int sub = 0; sub < 4; ++sub) {
      mv[sub] = mask[b * SS + k0g + sub * 16 + lo16];
      sc4[sub] = f32x4{0.f, 0.f, 0.f, 0.f};
      const int krow = sub * 16 + lo16;
#pragma unroll
      for (int c = 0; c < 2; ++c) {
        s16x8 kh = *(const s16x8*)&sKh[krow * PAD + c * 32 + quad * 8];
        s16x8 kl = *(const s16x8*)&sKl[krow * PAD + c * 32 + quad * 8];
        sc4[sub] = mfma16(qh[c], kh, sc4[sub]);
        sc4[sub] = mfma16(qh[c], kl, sc4[sub]);
      }
    }

#pragma unroll
    for (int sub = 0; sub < 4; ++sub)
#pragma unroll
      for (int r = 0; r < 4; ++r) {
        float p = exp2f(sc4[sub][r] * EXPSC);
        p = mv[sub] ? p : 0.f;
        lsum[r] += p;
        sP[wv][(quad * 4 + r) * PAD + sub * 16 + lo16] = f2bf_rne(p);
      }

    s16x8 pa[2];
#pragma unroll
    for (int c = 0; c < 2; ++c)
      pa[c] = *(const s16x8*)&sP[wv][lo16 * PAD + c * 32 + quad * 8];
#pragma unroll
    for (int t = 0; t < 4; ++t)
#pragma unroll
      for (int c = 0; c < 2; ++c) {
        s16x8 vb = *(const s16x8*)&sV[(t * 16 + lo16) * PAD + c * 32 + quad * 8];
        Oacc[t] = mfma16(pa[c], vb, Oacc[t]);
      }
    __syncthreads();
  }

  const int h = head & 15;
#pragma unroll
  for (int r = 0; r < 4; ++r) {
    float s = lsum[r];
#pragma unroll
    for (int off = 1; off < 16; off <<= 1) s += __shfl_xor(s, off);
    const float rinv = 1.0f / s;
#pragma unroll
    for (int t = 0; t < 4; ++t) {
      const float val = Oacc[t][r] * rinv;
      const int row = q0 + quad * 4 + r;
      const int col = h * DKK + t * 16 + lo16;
      const size_t idx = ((size_t)b * SS + row) * DD + col;
      short hh, ll;
      split1(val, hh, ll);
      Ah[idx] = hh;
      Al[idx] = ll;
    }
  }
}

// ---------------------------------------------------------------- launch
extern "C" void kernel_launch(void* const* d_in, const int* in_sizes, int n_in,
                              void* d_out, int out_size, void* d_ws, size_t ws_size,
                              hipStream_t stream) {
  const float* q = (const float*)d_in[0];
  const float* k = (const float*)d_in[1];
  const float* v = (const float*)d_in[2];
  const int* mask = (const int*)d_in[3];
  const float* Wq = (const float*)d_in[4];
  const float* bq = (const float*)d_in[5];
  const float* Wk = (const float*)d_in[6];
  const float* bk = (const float*)d_in[7];
  const float* Wv = (const float*)d_in[8];
  const float* bv = (const float*)d_in[9];
  const float* Wo = (const float*)d_in[10];
  const float* bo = (const float*)d_in[11];

  char* ws = (char*)d_ws;
  size_t off = 0;
  auto take = [&](size_t bytes) {
    char* p = ws + off;
    off += (bytes + 255) & ~(size_t)255;
    return p;
  };
  const size_t WE = (size_t)DD * DD;       // 1,048,576
  const size_t TE = (size_t)BB * SS * DD;  // 4,194,304

  short* Wqh = (short*)take(WE * 2);
  short* Wql = (short*)take(WE * 2);
  short* Wkh = (short*)take(WE * 2);
  short* Wkl = (short*)take(WE * 2);
  short* Wvh = (short*)take(WE * 2);
  short* Woh = (short*)take(WE * 2);
  short* Wol = (short*)take(WE * 2);
  short* qH = (short*)take(TE * 2);
  short* qL = (short*)take(TE * 2);
  short* kH = (short*)take(TE * 2);
  short* kL = (short*)take(TE * 2);
  short* Qh = (short*)take(TE * 2);
  short* Kh = (short*)take(TE * 2);
  short* Kl = (short*)take(TE * 2);
  (void)ws_size;  // 70 MB peak (aliased below)
  // aliases (lifetimes disjoint on the serial stream):
  short* vH = qH;  // v cast, after gemm_qk consumed qH
  short* Vt = qL;  // V-proj out, after gemm_qk consumed qL
  short* aH = kH;  // attn out hi, after gemm_qk consumed kH
  short* aL = kL;  // attn out lo

  // weights
  split_pair<<<1024, 256, 0, stream>>>(Wq, Wqh, Wql);
  split_pair<<<1024, 256, 0, stream>>>(Wk, Wkh, Wkl);
  split_pair<<<1024, 256, 0, stream>>>(Wo, Woh, Wol);
  cast_rne<<<1024, 256, 0, stream>>>(Wv, Wvh);

  // activation splits
  split_pair<<<4096, 256, 0, stream>>>(q, qH, qL);
  split_pair<<<4096, 256, 0, stream>>>(k, kH, kL);

  // merged Q+K projection (1024 blocks -> 3 blocks/CU)
  gemm_qk<<<1024, 256, 0, stream>>>(qH, qL, Wqh, Wql, bq, Qh,
                                    kH, kL, Wkh, Wkl, bk, Kh, Kl);

  // V projection (plain bf16, transposed output)
  cast_rne<<<4096, 256, 0, stream>>>(v, vH);
  gemm_tile<0, 1><<<512, 256, 0, stream>>>(vH, nullptr, Wvh, nullptr, bv, Vt, nullptr);

  // attention (512 x 512-thread blocks: 8 waves share each staged tile)
  mha_attn<<<512, 512, 0, stream>>>(Qh, Kh, Kl, Vt, mask, aH, aL);

  // output projection
  gemm_tile<1, 2><<<512, 256, 0, stream>>>(aH, aL, Woh, Wol, bo, d_out, nullptr);
}

// Round 4
// 322.889 us; speedup vs baseline: 1.2941x; 1.0496x over previous
//
#include <hip/hip_runtime.h>

// MHA fused: B=2, S=2048, D=1024, H=16, DK=64.
// Round 10:
//  - Structure probes R7-R9 proved occupancy (22->39%) doesn't move dur
//    (107/120/112us): per-wave critical path limits. Reverted to R6 geometry
//    (256 thr, 4 waves x 32 q-rows, grid 512, staged K/V, 107.4us baseline).
//  - P-path rebuilt: QK operands SWAPPED (mfma(K,Q) -> S[k][q], lane holds
//    consecutive k for one q-row), softmax packs pairs via v_cvt_pk_bf16_f32
//    (1 instr replaces 8-op scalar RNE) and stores with 16 ds_write_b32
//    instead of 32 scatter ds_write_b16. ~25% of tile cycles were conversion
//    + scatter; this deletes most of it. Numerics identical (RNE bf16).
//  - lsum now per-q-row per lane; epilogue reduce = shfl_xor(16,32) + shfl.

constexpr int BB = 2;
constexpr int SS = 2048;
constexpr int DD = 1024;
constexpr int HH = 16;
constexpr int DKK = 64;

typedef float f32x4 __attribute__((ext_vector_type(4)));
typedef __bf16 bf16x8 __attribute__((ext_vector_type(8)));
typedef short s16x8 __attribute__((ext_vector_type(8)));
typedef short s16x4 __attribute__((ext_vector_type(4)));

#define DEV static __device__ __forceinline__

DEV f32x4 mfma16(s16x8 a, s16x8 b, f32x4 c) {
  return __builtin_amdgcn_mfma_f32_16x16x32_bf16(
      __builtin_bit_cast(bf16x8, a), __builtin_bit_cast(bf16x8, b), c, 0, 0, 0);
}

DEV void split1(float x, short& h, short& l) {  // x ~= hi + lo (both bf16)
  unsigned u = __float_as_uint(x);
  h = (short)(u >> 16);
  float hf = __uint_as_float(u & 0xffff0000u);
  l = (short)(__float_as_uint(x - hf) >> 16);
}
DEV short f2bf_rne(float x) {  // round-to-nearest-even bf16
  unsigned u = __float_as_uint(x);
  return (short)((u + 0x7fffu + ((u >> 16) & 1u)) >> 16);
}
DEV unsigned cvtpk(float lo, float hi) {  // packs 2 f32 -> 2 bf16 (RNE)
  unsigned r;
  asm("v_cvt_pk_bf16_f32 %0, %1, %2" : "=v"(r) : "v"(lo), "v"(hi));
  return r;
}
DEV s16x8 load8s(const short* p) { return *(const s16x8*)p; }

DEV void gld_lds16(const short* g, short* l) {
  __builtin_amdgcn_global_load_lds(
      (const __attribute__((address_space(1))) void*)g,
      (__attribute__((address_space(3))) void*)l, 16, 0, 0);
}

// ---------------------------------------------------------------- elementwise
__global__ __launch_bounds__(256) void split_pair(const float* __restrict__ X,
                                                  short* __restrict__ H,
                                                  short* __restrict__ L) {
  int i = (blockIdx.x * 256 + threadIdx.x) * 4;
  float4 x = *(const float4*)(X + i);
  float xs[4] = {x.x, x.y, x.z, x.w};
  s16x4 h4, l4;
#pragma unroll
  for (int e = 0; e < 4; ++e) {
    short h, l;
    split1(xs[e], h, l);
    h4[e] = h;
    l4[e] = l;
  }
  *(s16x4*)(H + i) = h4;
  *(s16x4*)(L + i) = l4;
}

__global__ __launch_bounds__(256) void cast_rne(const float* __restrict__ X,
                                                short* __restrict__ Y) {
  int i = (blockIdx.x * 256 + threadIdx.x) * 4;
  float4 x = *(const float4*)(X + i);
  float xs[4] = {x.x, x.y, x.z, x.w};
  s16x4 y4;
#pragma unroll
  for (int e = 0; e < 4; ++e) y4[e] = f2bf_rne(xs[e]);
  *(s16x4*)(Y + i) = y4;
}

// ---------------------------------------------------------------- merged Q+K projection
// Grid 1024: blocks 0-511 compute Q tiles (plain bf16 out, [B,H,S,DK]),
// blocks 512-1023 compute K tiles (hi/lo bf16 out, [B,H,S,DK]).
// Tile 128(M) x 64(N), BK=32, LDS double-buffered split K-loop.
__global__ __launch_bounds__(256) void gemm_qk(
    const short* __restrict__ qAh, const short* __restrict__ qAl,
    const short* __restrict__ Wqh, const short* __restrict__ Wql,
    const float* __restrict__ bq, short* __restrict__ Qo,
    const short* __restrict__ kAh, const short* __restrict__ kAl,
    const short* __restrict__ Wkh, const short* __restrict__ Wkl,
    const float* __restrict__ bk, short* __restrict__ Kho,
    short* __restrict__ Klo) {
  __shared__ short lds[2][12288];

  const int tid = threadIdx.x;
  const int lane = tid & 63, wv = tid >> 6;
  const int lo16 = lane & 15, quad = lane >> 4;
  const int sel = blockIdx.x >> 9;  // 0 = Q, 1 = K
  const int bid = blockIdx.x & 511;
  const int m0 = (bid & 31) * 128;
  const int n0 = (bid >> 5) * 64;

  const short* Agh = sel ? kAh : qAh;
  const short* Agl = sel ? kAl : qAl;
  const short* Wgh = sel ? Wkh : Wqh;
  const short* Wgl = sel ? Wkl : Wql;
  const float* bias = sel ? bk : bq;

  f32x4 acc[2][4];
#pragma unroll
  for (int mt = 0; mt < 2; ++mt)
#pragma unroll
    for (int nt = 0; nt < 4; ++nt) acc[mt][nt] = f32x4{0.f, 0.f, 0.f, 0.f};

  const int rw = tid >> 2, qw = tid & 3;
  const int ra0 = tid >> 2, ra1 = (tid + 256) >> 2;

  auto stage = [&](int k0, int buf) {
    short* sAh = lds[buf];
    short* sAl = lds[buf] + 4096;
    short* sWh = lds[buf] + 8192;
    short* sWl = lds[buf] + 10240;
    gld_lds16(Wgh + (size_t)(n0 + rw) * DD + k0 + qw * 8, sWh + tid * 8);
    gld_lds16(Wgl + (size_t)(n0 + rw) * DD + k0 + qw * 8, sWl + tid * 8);
    gld_lds16(Agh + (size_t)(m0 + ra0) * DD + k0 + qw * 8, sAh + tid * 8);
    gld_lds16(Agh + (size_t)(m0 + ra1) * DD + k0 + qw * 8, sAh + (tid + 256) * 8);
    gld_lds16(Agl + (size_t)(m0 + ra0) * DD + k0 + qw * 8, sAl + tid * 8);
    gld_lds16(Agl + (size_t)(m0 + ra1) * DD + k0 + qw * 8, sAl + (tid + 256) * 8);
  };

  stage(0, 0);

  for (int kk = 0; kk < DD / 32; ++kk) {
    __syncthreads();
    if (kk + 1 < DD / 32) stage((kk + 1) * 32, (kk + 1) & 1);

    const short* sAh = lds[kk & 1];
    const short* sAl = lds[kk & 1] + 4096;
    const short* sWh = lds[kk & 1] + 8192;
    const short* sWl = lds[kk & 1] + 10240;

    s16x8 ah[2], al[2], wh[4], wl[4];
#pragma unroll
    for (int mt = 0; mt < 2; ++mt) {
      const int r = wv * 32 + mt * 16 + lo16;
      ah[mt] = *(const s16x8*)&sAh[r * 32 + quad * 8];
      al[mt] = *(const s16x8*)&sAl[r * 32 + quad * 8];
    }
#pragma unroll
    for (int nt = 0; nt < 4; ++nt) {
      const int r = nt * 16 + lo16;
      wh[nt] = *(const s16x8*)&sWh[r * 32 + quad * 8];
      wl[nt] = *(const s16x8*)&sWl[r * 32 + quad * 8];
    }
#pragma unroll
    for (int mt = 0; mt < 2; ++mt)
#pragma unroll
      for (int nt = 0; nt < 4; ++nt) {
        acc[mt][nt] = mfma16(ah[mt], wh[nt], acc[mt][nt]);
        acc[mt][nt] = mfma16(ah[mt], wl[nt], acc[mt][nt]);
        acc[mt][nt] = mfma16(al[mt], wh[nt], acc[mt][nt]);
      }
  }

#pragma unroll
  for (int mt = 0; mt < 2; ++mt)
#pragma unroll
    for (int nt = 0; nt < 4; ++nt) {
      const int n = n0 + nt * 16 + lo16;
      const float bv = bias[n];
#pragma unroll
      for (int r = 0; r < 4; ++r) {
        const int m = m0 + wv * 32 + mt * 16 + quad * 4 + r;
        const float val = acc[mt][nt][r] + bv;
        const int b = m >> 11, s = m & 2047;
        const int h = n >> 6, dk = n & 63;
        size_t idx = ((size_t)(b * HH + h) * SS + s) * DKK + dk;
        if (sel == 0) {
          Qo[idx] = f2bf_rne(val);
        } else {
          short hh, ll;
          split1(val, hh, ll);
          Kho[idx] = hh;
          Klo[idx] = ll;
        }
      }
    }
}

// ---------------------------------------------------------------- GEMM C = A @ W^T + b
// EPI 1: plain A/W, out bf16 -> [B,H,DK,S] (V transposed)
// EPI 2: split A/W, out fp32 -> [4096,1024] (final output)
template <int SPLIT, int EPI>
__global__ __launch_bounds__(256) void gemm_tile(
    const short* __restrict__ Agh, const short* __restrict__ Agl,
    const short* __restrict__ Wgh, const short* __restrict__ Wgl,
    const float* __restrict__ bias, void* __restrict__ O1, void* __restrict__ O2) {
  __shared__ short lds[2][12288];

  const int tid = threadIdx.x;
  const int lane = tid & 63, wv = tid >> 6;
  const int lo16 = lane & 15, quad = lane >> 4;
  const int m0 = (blockIdx.x & 31) * 128;
  const int n0 = (blockIdx.x >> 5) * 64;

  f32x4 acc[2][4];
#pragma unroll
  for (int mt = 0; mt < 2; ++mt)
#pragma unroll
    for (int nt = 0; nt < 4; ++nt) acc[mt][nt] = f32x4{0.f, 0.f, 0.f, 0.f};

  const int rw = tid >> 2, qw = tid & 3;
  const int ra0 = tid >> 2, ra1 = (tid + 256) >> 2;

  auto stage = [&](int k0, int buf) {
    short* sAh = lds[buf];
    short* sAl = lds[buf] + 4096;
    short* sWh = lds[buf] + 8192;
    short* sWl = lds[buf] + 10240;
    gld_lds16(Wgh + (size_t)(n0 + rw) * DD + k0 + qw * 8, sWh + tid * 8);
    if constexpr (SPLIT)
      gld_lds16(Wgl + (size_t)(n0 + rw) * DD + k0 + qw * 8, sWl + tid * 8);
    gld_lds16(Agh + (size_t)(m0 + ra0) * DD + k0 + qw * 8, sAh + tid * 8);
    gld_lds16(Agh + (size_t)(m0 + ra1) * DD + k0 + qw * 8, sAh + (tid + 256) * 8);
    if constexpr (SPLIT) {
      gld_lds16(Agl + (size_t)(m0 + ra0) * DD + k0 + qw * 8, sAl + tid * 8);
      gld_lds16(Agl + (size_t)(m0 + ra1) * DD + k0 + qw * 8, sAl + (tid + 256) * 8);
    }
  };

  stage(0, 0);

  for (int kk = 0; kk < DD / 32; ++kk) {
    __syncthreads();
    if (kk + 1 < DD / 32) stage((kk + 1) * 32, (kk + 1) & 1);

    const short* sAh = lds[kk & 1];
    const short* sAl = lds[kk & 1] + 4096;
    const short* sWh = lds[kk & 1] + 8192;
    const short* sWl = lds[kk & 1] + 10240;

    s16x8 ah[2], al[2], wh[4], wl[4];
#pragma unroll
    for (int mt = 0; mt < 2; ++mt) {
      const int r = wv * 32 + mt * 16 + lo16;
      ah[mt] = *(const s16x8*)&sAh[r * 32 + quad * 8];
      if constexpr (SPLIT) al[mt] = *(const s16x8*)&sAl[r * 32 + quad * 8];
    }
#pragma unroll
    for (int nt = 0; nt < 4; ++nt) {
      const int r = nt * 16 + lo16;
      wh[nt] = *(const s16x8*)&sWh[r * 32 + quad * 8];
      if constexpr (SPLIT) wl[nt] = *(const s16x8*)&sWl[r * 32 + quad * 8];
    }
#pragma unroll
    for (int mt = 0; mt < 2; ++mt)
#pragma unroll
      for (int nt = 0; nt < 4; ++nt) {
        acc[mt][nt] = mfma16(ah[mt], wh[nt], acc[mt][nt]);
        if constexpr (SPLIT) {
          acc[mt][nt] = mfma16(ah[mt], wl[nt], acc[mt][nt]);
          acc[mt][nt] = mfma16(al[mt], wh[nt], acc[mt][nt]);
        }
      }
  }

#pragma unroll
  for (int mt = 0; mt < 2; ++mt)
#pragma unroll
    for (int nt = 0; nt < 4; ++nt) {
      const int n = n0 + nt * 16 + lo16;
      const float bv = bias[n];
#pragma unroll
      for (int r = 0; r < 4; ++r) {
        const int m = m0 + wv * 32 + mt * 16 + quad * 4 + r;
        const float val = acc[mt][nt][r] + bv;
        const int b = m >> 11, s = m & 2047;
        const int h = n >> 6, dk = n & 63;
        if constexpr (EPI == 1) {
          size_t idx = ((size_t)(b * HH + h) * DKK + dk) * SS + s;
          ((short*)O1)[idx] = f2bf_rne(val);
        } else {
          ((float*)O1)[(size_t)m * DD + n] = val;
        }
      }
    }
}

// ---------------------------------------------------------------- flash attention
// Block = 128 q-rows of one head (4 waves x 32 rows), grid 512 (R6 geometry).
// K/V staged in LDS per 64-key iteration; next tile register-prefetched.
// SWAPPED QK: sc = mfma(K, Q) -> S[k][q]; lane holds 4 consecutive k per acc
// reg -> softmax P packed in pairs via v_cvt_pk_bf16_f32 and stored with
// ds_write_b32 (replaces 32x scalar-RNE + ds_write_b16 scatter).
// No-max softmax. Q plain bf16; K hi/lo (2-term QK MFMA).
constexpr int PAD = 68;
constexpr int NKB = SS / 64;  // 32
constexpr float EXPSC = 0.125f * 1.4426950408889634f;  // fold /sqrt(DK) into exp2

__global__ __launch_bounds__(256, 2) void mha_attn(
    const short* __restrict__ Qh, const short* __restrict__ Kh,
    const short* __restrict__ Kl, const short* __restrict__ Vt,
    const int* __restrict__ mask, short* __restrict__ Ah,
    short* __restrict__ Al) {
  __shared__ short sKh[64 * PAD];
  __shared__ short sKl[64 * PAD];
  __shared__ short sV[64 * PAD];
  __shared__ short sP[4][32 * PAD];

  const int tid = threadIdx.x;
  const int lane = tid & 63, wv = tid >> 6;
  const int lo16 = lane & 15, quad = lane >> 4;
  const int bid = blockIdx.x;                         // 512 blocks
  const int head = (bid & 7) * 4 + ((bid >> 3) & 3);  // = b*16 + h (head->XCD pin)
  const int qblk = bid >> 5;                          // 0..15
  const int q0 = qblk * 128 + wv * 32;                // this wave's 32 q rows
  const int b = head >> 4;

  const size_t hbase = (size_t)head * SS;

  s16x8 qh[2][2];
#pragma unroll
  for (int rt = 0; rt < 2; ++rt) {
    size_t qb = (hbase + q0 + rt * 16 + lo16) * DKK + quad * 8;
#pragma unroll
    for (int c = 0; c < 2; ++c) qh[rt][c] = load8s(Qh + qb + c * 32);
  }

  f32x4 Oacc[2][4];
#pragma unroll
  for (int rt = 0; rt < 2; ++rt)
#pragma unroll
    for (int t = 0; t < 4; ++t) Oacc[rt][t] = f32x4{0.f, 0.f, 0.f, 0.f};
  float lsum[2] = {0.f, 0.f};  // per-lane: q-row = q0 + rt*16 + lo16

  const int srow = tid >> 2;
  const int scol0 = (tid & 3) * 8;

  s16x8 rKh[2], rKl[2], rV[2];
#pragma unroll
  for (int i = 0; i < 2; ++i) {
    const int sc_ = scol0 + i * 32;
    rKh[i] = load8s(Kh + (hbase + srow) * DKK + sc_);
    rKl[i] = load8s(Kl + (hbase + srow) * DKK + sc_);
    rV[i] = load8s(Vt + ((size_t)head * DKK + srow) * SS + sc_);
  }

  for (int kb = 0; kb < NKB; ++kb) {
    const int k0g = kb * 64;
#pragma unroll
    for (int i = 0; i < 2; ++i) {
      const int sc_ = scol0 + i * 32;
      *(s16x8*)&sKh[srow * PAD + sc_] = rKh[i];
      *(s16x8*)&sKl[srow * PAD + sc_] = rKl[i];
      *(s16x8*)&sV[srow * PAD + sc_] = rV[i];
    }
    __syncthreads();

    if (kb + 1 < NKB) {
      const int k0n = k0g + 64;
#pragma unroll
      for (int i = 0; i < 2; ++i) {
        const int sc_ = scol0 + i * 32;
        rKh[i] = load8s(Kh + (hbase + k0n + srow) * DKK + sc_);
        rKl[i] = load8s(Kl + (hbase + k0n + srow) * DKK + sc_);
        rV[i] = load8s(Vt + ((size_t)head * DKK + srow) * SS + k0n + sc_);
      }
    }

    // mask for this tile's k rows: k = sub*16 + quad*4 + r (int4 per sub)
    int mvs[4][4];
#pragma unroll
    for (int sub = 0; sub < 4; ++sub) {
      const int4 mq = *(const int4*)(mask + b * SS + k0g + sub * 16 + quad * 4);
      mvs[sub][0] = mq.x;
      mvs[sub][1] = mq.y;
      mvs[sub][2] = mq.z;
      mvs[sub][3] = mq.w;
    }

    // ---- QK^T (swapped): sc4[rt][sub][r] = S[k = sub*16+quad*4+r][q = q0+rt*16+lo16]
    f32x4 sc4[2][4];
#pragma unroll
    for (int sub = 0; sub < 4; ++sub) {
      sc4[0][sub] = f32x4{0.f, 0.f, 0.f, 0.f};
      sc4[1][sub] = f32x4{0.f, 0.f, 0.f, 0.f};
      const int krow = sub * 16 + lo16;
#pragma unroll
      for (int c = 0; c < 2; ++c) {
        s16x8 kh = *(const s16x8*)&sKh[krow * PAD + c * 32 + quad * 8];
        s16x8 kl = *(const s16x8*)&sKl[krow * PAD + c * 32 + quad * 8];
#pragma unroll
        for (int rt = 0; rt < 2; ++rt) {
          sc4[rt][sub] = mfma16(kh, qh[rt][c], sc4[rt][sub]);
          sc4[rt][sub] = mfma16(kl, qh[rt][c], sc4[rt][sub]);
        }
      }
    }

    // ---- softmax (no-max), pack pairs, packed b32 stores into row-major P
#pragma unroll
    for (int rt = 0; rt < 2; ++rt) {
      const int prow = (rt * 16 + lo16) * PAD;
#pragma unroll
      for (int sub = 0; sub < 4; ++sub) {
        float p[4];
#pragma unroll
        for (int r = 0; r < 4; ++r) {
          float e = exp2f(sc4[rt][sub][r] * EXPSC);
          e = mvs[sub][r] ? e : 0.f;
          lsum[rt] += e;
          p[r] = e;
        }
        const unsigned w0 = cvtpk(p[0], p[1]);
        const unsigned w1 = cvtpk(p[2], p[3]);
        *(unsigned*)&sP[wv][prow + sub * 16 + quad * 4] = w0;
        *(unsigned*)&sP[wv][prow + sub * 16 + quad * 4 + 2] = w1;
      }
    }

    // ---- PV
    s16x8 pa[2][2];
#pragma unroll
    for (int rt = 0; rt < 2; ++rt)
#pragma unroll
      for (int c = 0; c < 2; ++c)
        pa[rt][c] = *(const s16x8*)&sP[wv][(rt * 16 + lo16) * PAD + c * 32 + quad * 8];
#pragma unroll
    for (int t = 0; t < 4; ++t)
#pragma unroll
      for (int c = 0; c < 2; ++c) {
        s16x8 vb = *(const s16x8*)&sV[(t * 16 + lo16) * PAD + c * 32 + quad * 8];
#pragma unroll
        for (int rt = 0; rt < 2; ++rt)
          Oacc[rt][t] = mfma16(pa[rt][c], vb, Oacc[rt][t]);
      }
    __syncthreads();
  }

  const int h = head & 15;
#pragma unroll
  for (int rt = 0; rt < 2; ++rt) {
    // lsum[rt] holds this lane's partial (16 of 64 k's) for q = q0+rt*16+lo16;
    // full row sum = reduce across the 4 quad groups.
    float s = lsum[rt];
    s += __shfl_xor(s, 16);
    s += __shfl_xor(s, 32);
#pragma unroll
    for (int r = 0; r < 4; ++r) {
      // output row q_local = quad*4 + r needs the sum held at lane (quad*4+r)
      const float rinv = 1.0f / __shfl(s, quad * 4 + r);
#pragma unroll
      for (int t = 0; t < 4; ++t) {
        const float val = Oacc[rt][t][r] * rinv;
        const int row = q0 + rt * 16 + quad * 4 + r;
        const int col = h * DKK + t * 16 + lo16;
        const size_t idx = ((size_t)b * SS + row) * DD + col;
        short hh, ll;
        split1(val, hh, ll);
        Ah[idx] = hh;
        Al[idx] = ll;
      }
    }
  }
}

// ---------------------------------------------------------------- launch
extern "C" void kernel_launch(void* const* d_in, const int* in_sizes, int n_in,
                              void* d_out, int out_size, void* d_ws, size_t ws_size,
                              hipStream_t stream) {
  const float* q = (const float*)d_in[0];
  const float* k = (const float*)d_in[1];
  const float* v = (const float*)d_in[2];
  const int* mask = (const int*)d_in[3];
  const float* Wq = (const float*)d_in[4];
  const float* bq = (const float*)d_in[5];
  const float* Wk = (const float*)d_in[6];
  const float* bk = (const float*)d_in[7];
  const float* Wv = (const float*)d_in[8];
  const float* bv = (const float*)d_in[9];
  const float* Wo = (const float*)d_in[10];
  const float* bo = (const float*)d_in[11];

  char* ws = (char*)d_ws;
  size_t off = 0;
  auto take = [&](size_t bytes) {
    char* p = ws + off;
    off += (bytes + 255) & ~(size_t)255;
    return p;
  };
  const size_t WE = (size_t)DD * DD;       // 1,048,576
  const size_t TE = (size_t)BB * SS * DD;  // 4,194,304

  short* Wqh = (short*)take(WE * 2);
  short* Wql = (short*)take(WE * 2);
  short* Wkh = (short*)take(WE * 2);
  short* Wkl = (short*)take(WE * 2);
  short* Wvh = (short*)take(WE * 2);
  short* Woh = (short*)take(WE * 2);
  short* Wol = (short*)take(WE * 2);
  short* qH = (short*)take(TE * 2);
  short* qL = (short*)take(TE * 2);
  short* kH = (short*)take(TE * 2);
  short* kL = (short*)take(TE * 2);
  short* Qh = (short*)take(TE * 2);
  short* Kh = (short*)take(TE * 2);
  short* Kl = (short*)take(TE * 2);
  (void)ws_size;  // 70 MB peak (aliased below)
  // aliases (lifetimes disjoint on the serial stream):
  short* vH = qH;  // v cast, after gemm_qk consumed qH
  short* Vt = qL;  // V-proj out, after gemm_qk consumed qL
  short* aH = kH;  // attn out hi, after gemm_qk consumed kH
  short* aL = kL;  // attn out lo

  // weights
  split_pair<<<1024, 256, 0, stream>>>(Wq, Wqh, Wql);
  split_pair<<<1024, 256, 0, stream>>>(Wk, Wkh, Wkl);
  split_pair<<<1024, 256, 0, stream>>>(Wo, Woh, Wol);
  cast_rne<<<1024, 256, 0, stream>>>(Wv, Wvh);

  // activation splits
  split_pair<<<4096, 256, 0, stream>>>(q, qH, qL);
  split_pair<<<4096, 256, 0, stream>>>(k, kH, kL);

  // merged Q+K projection (1024 blocks -> 3 blocks/CU)
  gemm_qk<<<1024, 256, 0, stream>>>(qH, qL, Wqh, Wql, bq, Qh,
                                    kH, kL, Wkh, Wkl, bk, Kh, Kl);

  // V projection (plain bf16, transposed output)
  cast_rne<<<4096, 256, 0, stream>>>(v, vH);
  gemm_tile<0, 1><<<512, 256, 0, stream>>>(vH, nullptr, Wvh, nullptr, bv, Vt, nullptr);

  // attention (R6 geometry + swapped-QK packed-P softmax)
  mha_attn<<<512, 256, 0, stream>>>(Qh, Kh, Kl, Vt, mask, aH, aL);

  // output projection
  gemm_tile<1, 2><<<512, 256, 0, stream>>>(aH, aL, Woh, Wol, bo, d_out, nullptr);
}

// Round 5
// 318.452 us; speedup vs baseline: 1.3121x; 1.0139x over previous
//
#include <hip/hip_runtime.h>

// MHA fused: B=2, S=2048, D=1024, H=16, DK=64.
// Round 11:
//  - R10 (swapped-QK + cvt_pk P-path) WON: attn 107.4->94.8us. Kept.
//  - Softmax VALU cut further: (a) mask folded into exp arg via precomputed
//    addend (-32768 -> exp2 underflows to exact 0): 32 fma + 16 sel replaces
//    32 mul + 32 cndmask. (b) row-sum moved to MFMA pipe: sacc = mfma(pa,
//    ones, sacc); C/D layout lands sum in the exact epilogue register ->
//    deletes 32 serial adds + the shuffle reduce. MFMA pipe 22% vs VALU 49%.
//  - T5 s_setprio(1) around both MFMA clusters (m191: +4-7% attn).
//  - 7 elementwise launches merged into 1 `prep` kernel (v-cast stays
//    separate: vH aliases qH which gemm_qk reads). 9 -> 6 dispatches.

constexpr int BB = 2;
constexpr int SS = 2048;
constexpr int DD = 1024;
constexpr int HH = 16;
constexpr int DKK = 64;

typedef float f32x4 __attribute__((ext_vector_type(4)));
typedef __bf16 bf16x8 __attribute__((ext_vector_type(8)));
typedef short s16x8 __attribute__((ext_vector_type(8)));
typedef short s16x4 __attribute__((ext_vector_type(4)));

#define DEV static __device__ __forceinline__

DEV f32x4 mfma16(s16x8 a, s16x8 b, f32x4 c) {
  return __builtin_amdgcn_mfma_f32_16x16x32_bf16(
      __builtin_bit_cast(bf16x8, a), __builtin_bit_cast(bf16x8, b), c, 0, 0, 0);
}

DEV void split1(float x, short& h, short& l) {  // x ~= hi + lo (both bf16)
  unsigned u = __float_as_uint(x);
  h = (short)(u >> 16);
  float hf = __uint_as_float(u & 0xffff0000u);
  l = (short)(__float_as_uint(x - hf) >> 16);
}
DEV short f2bf_rne(float x) {  // round-to-nearest-even bf16
  unsigned u = __float_as_uint(x);
  return (short)((u + 0x7fffu + ((u >> 16) & 1u)) >> 16);
}
DEV unsigned cvtpk(float lo, float hi) {  // packs 2 f32 -> 2 bf16 (RNE)
  unsigned r;
  asm("v_cvt_pk_bf16_f32 %0, %1, %2" : "=v"(r) : "v"(lo), "v"(hi));
  return r;
}
DEV s16x8 load8s(const short* p) { return *(const s16x8*)p; }

DEV void gld_lds16(const short* g, short* l) {
  __builtin_amdgcn_global_load_lds(
      (const __attribute__((address_space(1))) void*)g,
      (__attribute__((address_space(3))) void*)l, 16, 0, 0);
}

// ---------------------------------------------------------------- elementwise
DEV void split4(const float* __restrict__ X, short* __restrict__ H,
                short* __restrict__ L, int i) {
  float4 x = *(const float4*)(X + i);
  float xs[4] = {x.x, x.y, x.z, x.w};
  s16x4 h4, l4;
#pragma unroll
  for (int e = 0; e < 4; ++e) {
    short h, l;
    split1(xs[e], h, l);
    h4[e] = h;
    l4[e] = l;
  }
  *(s16x4*)(H + i) = h4;
  *(s16x4*)(L + i) = l4;
}

DEV void cast4(const float* __restrict__ X, short* __restrict__ Y, int i) {
  float4 x = *(const float4*)(X + i);
  float xs[4] = {x.x, x.y, x.z, x.w};
  s16x4 y4;
#pragma unroll
  for (int e = 0; e < 4; ++e) y4[e] = f2bf_rne(xs[e]);
  *(s16x4*)(Y + i) = y4;
}

// merged elementwise pre-pass:
// blocks [0,1024) Wq split | [1024,2048) Wk split | [2048,3072) Wo split |
// [3072,4096) Wv cast | [4096,8192) q split | [8192,12288) k split.
// (v cast NOT here: vH aliases qH, which gemm_qk still reads.)
__global__ __launch_bounds__(256) void prep(
    const float* __restrict__ Wq, short* __restrict__ Wqh, short* __restrict__ Wql,
    const float* __restrict__ Wk, short* __restrict__ Wkh, short* __restrict__ Wkl,
    const float* __restrict__ Wo, short* __restrict__ Woh, short* __restrict__ Wol,
    const float* __restrict__ Wv, short* __restrict__ Wvh,
    const float* __restrict__ q, short* __restrict__ qH, short* __restrict__ qL,
    const float* __restrict__ k, short* __restrict__ kH, short* __restrict__ kL) {
  const int bid = blockIdx.x;
  const int t = threadIdx.x;
  if (bid < 4096) {
    const int w = bid >> 10;  // 0..3
    const int i = ((bid & 1023) * 256 + t) * 4;
    if (w == 0) split4(Wq, Wqh, Wql, i);
    else if (w == 1) split4(Wk, Wkh, Wkl, i);
    else if (w == 2) split4(Wo, Woh, Wol, i);
    else cast4(Wv, Wvh, i);
  } else {
    const int a = (bid - 4096) >> 12;  // 0..1
    const int i = (((bid - 4096) & 4095) * 256 + t) * 4;
    if (a == 0) split4(q, qH, qL, i);
    else split4(k, kH, kL, i);
  }
}

__global__ __launch_bounds__(256) void cast_rne(const float* __restrict__ X,
                                                short* __restrict__ Y) {
  int i = (blockIdx.x * 256 + threadIdx.x) * 4;
  cast4(X, Y, i);
}

// ---------------------------------------------------------------- merged Q+K projection
// Grid 1024: blocks 0-511 compute Q tiles (plain bf16 out, [B,H,S,DK]),
// blocks 512-1023 compute K tiles (hi/lo bf16 out, [B,H,S,DK]).
// Tile 128(M) x 64(N), BK=32, LDS double-buffered split K-loop.
__global__ __launch_bounds__(256) void gemm_qk(
    const short* __restrict__ qAh, const short* __restrict__ qAl,
    const short* __restrict__ Wqh, const short* __restrict__ Wql,
    const float* __restrict__ bq, short* __restrict__ Qo,
    const short* __restrict__ kAh, const short* __restrict__ kAl,
    const short* __restrict__ Wkh, const short* __restrict__ Wkl,
    const float* __restrict__ bk, short* __restrict__ Kho,
    short* __restrict__ Klo) {
  __shared__ short lds[2][12288];

  const int tid = threadIdx.x;
  const int lane = tid & 63, wv = tid >> 6;
  const int lo16 = lane & 15, quad = lane >> 4;
  const int sel = blockIdx.x >> 9;  // 0 = Q, 1 = K
  const int bid = blockIdx.x & 511;
  const int m0 = (bid & 31) * 128;
  const int n0 = (bid >> 5) * 64;

  const short* Agh = sel ? kAh : qAh;
  const short* Agl = sel ? kAl : qAl;
  const short* Wgh = sel ? Wkh : Wqh;
  const short* Wgl = sel ? Wkl : Wql;
  const float* bias = sel ? bk : bq;

  f32x4 acc[2][4];
#pragma unroll
  for (int mt = 0; mt < 2; ++mt)
#pragma unroll
    for (int nt = 0; nt < 4; ++nt) acc[mt][nt] = f32x4{0.f, 0.f, 0.f, 0.f};

  const int rw = tid >> 2, qw = tid & 3;
  const int ra0 = tid >> 2, ra1 = (tid + 256) >> 2;

  auto stage = [&](int k0, int buf) {
    short* sAh = lds[buf];
    short* sAl = lds[buf] + 4096;
    short* sWh = lds[buf] + 8192;
    short* sWl = lds[buf] + 10240;
    gld_lds16(Wgh + (size_t)(n0 + rw) * DD + k0 + qw * 8, sWh + tid * 8);
    gld_lds16(Wgl + (size_t)(n0 + rw) * DD + k0 + qw * 8, sWl + tid * 8);
    gld_lds16(Agh + (size_t)(m0 + ra0) * DD + k0 + qw * 8, sAh + tid * 8);
    gld_lds16(Agh + (size_t)(m0 + ra1) * DD + k0 + qw * 8, sAh + (tid + 256) * 8);
    gld_lds16(Agl + (size_t)(m0 + ra0) * DD + k0 + qw * 8, sAl + tid * 8);
    gld_lds16(Agl + (size_t)(m0 + ra1) * DD + k0 + qw * 8, sAl + (tid + 256) * 8);
  };

  stage(0, 0);

  for (int kk = 0; kk < DD / 32; ++kk) {
    __syncthreads();
    if (kk + 1 < DD / 32) stage((kk + 1) * 32, (kk + 1) & 1);

    const short* sAh = lds[kk & 1];
    const short* sAl = lds[kk & 1] + 4096;
    const short* sWh = lds[kk & 1] + 8192;
    const short* sWl = lds[kk & 1] + 10240;

    s16x8 ah[2], al[2], wh[4], wl[4];
#pragma unroll
    for (int mt = 0; mt < 2; ++mt) {
      const int r = wv * 32 + mt * 16 + lo16;
      ah[mt] = *(const s16x8*)&sAh[r * 32 + quad * 8];
      al[mt] = *(const s16x8*)&sAl[r * 32 + quad * 8];
    }
#pragma unroll
    for (int nt = 0; nt < 4; ++nt) {
      const int r = nt * 16 + lo16;
      wh[nt] = *(const s16x8*)&sWh[r * 32 + quad * 8];
      wl[nt] = *(const s16x8*)&sWl[r * 32 + quad * 8];
    }
#pragma unroll
    for (int mt = 0; mt < 2; ++mt)
#pragma unroll
      for (int nt = 0; nt < 4; ++nt) {
        acc[mt][nt] = mfma16(ah[mt], wh[nt], acc[mt][nt]);
        acc[mt][nt] = mfma16(ah[mt], wl[nt], acc[mt][nt]);
        acc[mt][nt] = mfma16(al[mt], wh[nt], acc[mt][nt]);
      }
  }

#pragma unroll
  for (int mt = 0; mt < 2; ++mt)
#pragma unroll
    for (int nt = 0; nt < 4; ++nt) {
      const int n = n0 + nt * 16 + lo16;
      const float bv = bias[n];
#pragma unroll
      for (int r = 0; r < 4; ++r) {
        const int m = m0 + wv * 32 + mt * 16 + quad * 4 + r;
        const float val = acc[mt][nt][r] + bv;
        const int b = m >> 11, s = m & 2047;
        const int h = n >> 6, dk = n & 63;
        size_t idx = ((size_t)(b * HH + h) * SS + s) * DKK + dk;
        if (sel == 0) {
          Qo[idx] = f2bf_rne(val);
        } else {
          short hh, ll;
          split1(val, hh, ll);
          Kho[idx] = hh;
          Klo[idx] = ll;
        }
      }
    }
}

// ---------------------------------------------------------------- GEMM C = A @ W^T + b
// EPI 1: plain A/W, out bf16 -> [B,H,DK,S] (V transposed)
// EPI 2: split A/W, out fp32 -> [4096,1024] (final output)
template <int SPLIT, int EPI>
__global__ __launch_bounds__(256) void gemm_tile(
    const short* __restrict__ Agh, const short* __restrict__ Agl,
    const short* __restrict__ Wgh, const short* __restrict__ Wgl,
    const float* __restrict__ bias, void* __restrict__ O1, void* __restrict__ O2) {
  __shared__ short lds[2][12288];

  const int tid = threadIdx.x;
  const int lane = tid & 63, wv = tid >> 6;
  const int lo16 = lane & 15, quad = lane >> 4;
  const int m0 = (blockIdx.x & 31) * 128;
  const int n0 = (blockIdx.x >> 5) * 64;

  f32x4 acc[2][4];
#pragma unroll
  for (int mt = 0; mt < 2; ++mt)
#pragma unroll
    for (int nt = 0; nt < 4; ++nt) acc[mt][nt] = f32x4{0.f, 0.f, 0.f, 0.f};

  const int rw = tid >> 2, qw = tid & 3;
  const int ra0 = tid >> 2, ra1 = (tid + 256) >> 2;

  auto stage = [&](int k0, int buf) {
    short* sAh = lds[buf];
    short* sAl = lds[buf] + 4096;
    short* sWh = lds[buf] + 8192;
    short* sWl = lds[buf] + 10240;
    gld_lds16(Wgh + (size_t)(n0 + rw) * DD + k0 + qw * 8, sWh + tid * 8);
    if constexpr (SPLIT)
      gld_lds16(Wgl + (size_t)(n0 + rw) * DD + k0 + qw * 8, sWl + tid * 8);
    gld_lds16(Agh + (size_t)(m0 + ra0) * DD + k0 + qw * 8, sAh + tid * 8);
    gld_lds16(Agh + (size_t)(m0 + ra1) * DD + k0 + qw * 8, sAh + (tid + 256) * 8);
    if constexpr (SPLIT) {
      gld_lds16(Agl + (size_t)(m0 + ra0) * DD + k0 + qw * 8, sAl + tid * 8);
      gld_lds16(Agl + (size_t)(m0 + ra1) * DD + k0 + qw * 8, sAl + (tid + 256) * 8);
    }
  };

  stage(0, 0);

  for (int kk = 0; kk < DD / 32; ++kk) {
    __syncthreads();
    if (kk + 1 < DD / 32) stage((kk + 1) * 32, (kk + 1) & 1);

    const short* sAh = lds[kk & 1];
    const short* sAl = lds[kk & 1] + 4096;
    const short* sWh = lds[kk & 1] + 8192;
    const short* sWl = lds[kk & 1] + 10240;

    s16x8 ah[2], al[2], wh[4], wl[4];
#pragma unroll
    for (int mt = 0; mt < 2; ++mt) {
      const int r = wv * 32 + mt * 16 + lo16;
      ah[mt] = *(const s16x8*)&sAh[r * 32 + quad * 8];
      if constexpr (SPLIT) al[mt] = *(const s16x8*)&sAl[r * 32 + quad * 8];
    }
#pragma unroll
    for (int nt = 0; nt < 4; ++nt) {
      const int r = nt * 16 + lo16;
      wh[nt] = *(const s16x8*)&sWh[r * 32 + quad * 8];
      if constexpr (SPLIT) wl[nt] = *(const s16x8*)&sWl[r * 32 + quad * 8];
    }
#pragma unroll
    for (int mt = 0; mt < 2; ++mt)
#pragma unroll
      for (int nt = 0; nt < 4; ++nt) {
        acc[mt][nt] = mfma16(ah[mt], wh[nt], acc[mt][nt]);
        if constexpr (SPLIT) {
          acc[mt][nt] = mfma16(ah[mt], wl[nt], acc[mt][nt]);
          acc[mt][nt] = mfma16(al[mt], wh[nt], acc[mt][nt]);
        }
      }
  }

#pragma unroll
  for (int mt = 0; mt < 2; ++mt)
#pragma unroll
    for (int nt = 0; nt < 4; ++nt) {
      const int n = n0 + nt * 16 + lo16;
      const float bv = bias[n];
#pragma unroll
      for (int r = 0; r < 4; ++r) {
        const int m = m0 + wv * 32 + mt * 16 + quad * 4 + r;
        const float val = acc[mt][nt][r] + bv;
        const int b = m >> 11, s = m & 2047;
        const int h = n >> 6, dk = n & 63;
        if constexpr (EPI == 1) {
          size_t idx = ((size_t)(b * HH + h) * DKK + dk) * SS + s;
          ((short*)O1)[idx] = f2bf_rne(val);
        } else {
          ((float*)O1)[(size_t)m * DD + n] = val;
        }
      }
    }
}

// ---------------------------------------------------------------- flash attention
// Block = 128 q-rows of one head (4 waves x 32 rows), grid 512 (R6 geometry).
// K/V staged in LDS per 64-key iteration; next tile register-prefetched.
// SWAPPED QK (S[k][q]); P packed via v_cvt_pk_bf16_f32 + b32 stores.
// Mask folded into exp arg (addend -32768 -> exp2 underflow = exact 0).
// Row-sum on MFMA pipe: sacc = mfma(pa, ones) -> sum lands in the epilogue's
// exact register slot (no shuffles). setprio(1) around MFMA clusters (T5).
constexpr int PAD = 68;
constexpr int NKB = SS / 64;  // 32
constexpr float EXPSC = 0.125f * 1.4426950408889634f;  // fold /sqrt(DK) into exp2

__global__ __launch_bounds__(256, 2) void mha_attn(
    const short* __restrict__ Qh, const short* __restrict__ Kh,
    const short* __restrict__ Kl, const short* __restrict__ Vt,
    const int* __restrict__ mask, short* __restrict__ Ah,
    short* __restrict__ Al) {
  __shared__ short sKh[64 * PAD];
  __shared__ short sKl[64 * PAD];
  __shared__ short sV[64 * PAD];
  __shared__ short sP[4][32 * PAD];

  const int tid = threadIdx.x;
  const int lane = tid & 63, wv = tid >> 6;
  const int lo16 = lane & 15, quad = lane >> 4;
  const int bid = blockIdx.x;                         // 512 blocks
  const int head = (bid & 7) * 4 + ((bid >> 3) & 3);  // = b*16 + h (head->XCD pin)
  const int qblk = bid >> 5;                          // 0..15
  const int q0 = qblk * 128 + wv * 32;                // this wave's 32 q rows
  const int b = head >> 4;

  const size_t hbase = (size_t)head * SS;

  constexpr short ONE_BF = (short)0x3F80;
  const s16x8 ones8 = {ONE_BF, ONE_BF, ONE_BF, ONE_BF,
                       ONE_BF, ONE_BF, ONE_BF, ONE_BF};

  s16x8 qh[2][2];
#pragma unroll
  for (int rt = 0; rt < 2; ++rt) {
    size_t qb = (hbase + q0 + rt * 16 + lo16) * DKK + quad * 8;
#pragma unroll
    for (int c = 0; c < 2; ++c) qh[rt][c] = load8s(Qh + qb + c * 32);
  }

  f32x4 Oacc[2][4];
#pragma unroll
  for (int rt = 0; rt < 2; ++rt)
#pragma unroll
    for (int t = 0; t < 4; ++t) Oacc[rt][t] = f32x4{0.f, 0.f, 0.f, 0.f};
  f32x4 sacc[2];  // row-sums via MFMA vs ones; sacc[rt][r] = rowsum(q0+rt*16+quad*4+r)
  sacc[0] = f32x4{0.f, 0.f, 0.f, 0.f};
  sacc[1] = f32x4{0.f, 0.f, 0.f, 0.f};

  const int srow = tid >> 2;
  const int scol0 = (tid & 3) * 8;

  s16x8 rKh[2], rKl[2], rV[2];
#pragma unroll
  for (int i = 0; i < 2; ++i) {
    const int sc_ = scol0 + i * 32;
    rKh[i] = load8s(Kh + (hbase + srow) * DKK + sc_);
    rKl[i] = load8s(Kl + (hbase + srow) * DKK + sc_);
    rV[i] = load8s(Vt + ((size_t)head * DKK + srow) * SS + sc_);
  }

  for (int kb = 0; kb < NKB; ++kb) {
    const int k0g = kb * 64;
#pragma unroll
    for (int i = 0; i < 2; ++i) {
      const int sc_ = scol0 + i * 32;
      *(s16x8*)&sKh[srow * PAD + sc_] = rKh[i];
      *(s16x8*)&sKl[srow * PAD + sc_] = rKl[i];
      *(s16x8*)&sV[srow * PAD + sc_] = rV[i];
    }
    __syncthreads();

    if (kb + 1 < NKB) {
      const int k0n = k0g + 64;
#pragma unroll
      for (int i = 0; i < 2; ++i) {
        const int sc_ = scol0 + i * 32;
        rKh[i] = load8s(Kh + (hbase + k0n + srow) * DKK + sc_);
        rKl[i] = load8s(Kl + (hbase + k0n + srow) * DKK + sc_);
        rV[i] = load8s(Vt + ((size_t)head * DKK + srow) * SS + k0n + sc_);
      }
    }

    // mask -> exp addend: 0 (keep) or -32768 (exp2 underflows to exact 0)
    float addf[4][4];
#pragma unroll
    for (int sub = 0; sub < 4; ++sub) {
      const int4 mq = *(const int4*)(mask + b * SS + k0g + sub * 16 + quad * 4);
      addf[sub][0] = mq.x ? 0.f : -32768.f;
      addf[sub][1] = mq.y ? 0.f : -32768.f;
      addf[sub][2] = mq.z ? 0.f : -32768.f;
      addf[sub][3] = mq.w ? 0.f : -32768.f;
    }

    // ---- QK^T (swapped): sc4[rt][sub][r] = S[k = sub*16+quad*4+r][q = q0+rt*16+lo16]
    f32x4 sc4[2][4];
    __builtin_amdgcn_s_setprio(1);
#pragma unroll
    for (int sub = 0; sub < 4; ++sub) {
      sc4[0][sub] = f32x4{0.f, 0.f, 0.f, 0.f};
      sc4[1][sub] = f32x4{0.f, 0.f, 0.f, 0.f};
      const int krow = sub * 16 + lo16;
#pragma unroll
      for (int c = 0; c < 2; ++c) {
        s16x8 kh = *(const s16x8*)&sKh[krow * PAD + c * 32 + quad * 8];
        s16x8 kl = *(const s16x8*)&sKl[krow * PAD + c * 32 + quad * 8];
#pragma unroll
        for (int rt = 0; rt < 2; ++rt) {
          sc4[rt][sub] = mfma16(kh, qh[rt][c], sc4[rt][sub]);
          sc4[rt][sub] = mfma16(kl, qh[rt][c], sc4[rt][sub]);
        }
      }
    }
    __builtin_amdgcn_s_setprio(0);

    // ---- softmax (no-max): p = exp2(fma(s, c, addend)), pack, b32 stores
#pragma unroll
    for (int rt = 0; rt < 2; ++rt) {
      const int prow = (rt * 16 + lo16) * PAD;
#pragma unroll
      for (int sub = 0; sub < 4; ++sub) {
        const float p0 = exp2f(fmaf(sc4[rt][sub][0], EXPSC, addf[sub][0]));
        const float p1 = exp2f(fmaf(sc4[rt][sub][1], EXPSC, addf[sub][1]));
        const float p2 = exp2f(fmaf(sc4[rt][sub][2], EXPSC, addf[sub][2]));
        const float p3 = exp2f(fmaf(sc4[rt][sub][3], EXPSC, addf[sub][3]));
        *(unsigned*)&sP[wv][prow + sub * 16 + quad * 4] = cvtpk(p0, p1);
        *(unsigned*)&sP[wv][prow + sub * 16 + quad * 4 + 2] = cvtpk(p2, p3);
      }
    }

    // ---- row-sum (MFMA vs ones) + PV
    s16x8 pa[2][2];
#pragma unroll
    for (int rt = 0; rt < 2; ++rt)
#pragma unroll
      for (int c = 0; c < 2; ++c)
        pa[rt][c] = *(const s16x8*)&sP[wv][(rt * 16 + lo16) * PAD + c * 32 + quad * 8];
    __builtin_amdgcn_s_setprio(1);
#pragma unroll
    for (int rt = 0; rt < 2; ++rt) {
      sacc[rt] = mfma16(pa[rt][0], ones8, sacc[rt]);
      sacc[rt] = mfma16(pa[rt][1], ones8, sacc[rt]);
    }
#pragma unroll
    for (int t = 0; t < 4; ++t)
#pragma unroll
      for (int c = 0; c < 2; ++c) {
        s16x8 vb = *(const s16x8*)&sV[(t * 16 + lo16) * PAD + c * 32 + quad * 8];
#pragma unroll
        for (int rt = 0; rt < 2; ++rt)
          Oacc[rt][t] = mfma16(pa[rt][c], vb, Oacc[rt][t]);
      }
    __builtin_amdgcn_s_setprio(0);
    __syncthreads();
  }

  const int h = head & 15;
#pragma unroll
  for (int rt = 0; rt < 2; ++rt) {
#pragma unroll
    for (int r = 0; r < 4; ++r) {
      const float rinv = 1.0f / sacc[rt][r];
#pragma unroll
      for (int t = 0; t < 4; ++t) {
        const float val = Oacc[rt][t][r] * rinv;
        const int row = q0 + rt * 16 + quad * 4 + r;
        const int col = h * DKK + t * 16 + lo16;
        const size_t idx = ((size_t)b * SS + row) * DD + col;
        short hh, ll;
        split1(val, hh, ll);
        Ah[idx] = hh;
        Al[idx] = ll;
      }
    }
  }
}

// ---------------------------------------------------------------- launch
extern "C" void kernel_launch(void* const* d_in, const int* in_sizes, int n_in,
                              void* d_out, int out_size, void* d_ws, size_t ws_size,
                              hipStream_t stream) {
  const float* q = (const float*)d_in[0];
  const float* k = (const float*)d_in[1];
  const float* v = (const float*)d_in[2];
  const int* mask = (const int*)d_in[3];
  const float* Wq = (const float*)d_in[4];
  const float* bq = (const float*)d_in[5];
  const float* Wk = (const float*)d_in[6];
  const float* bk = (const float*)d_in[7];
  const float* Wv = (const float*)d_in[8];
  const float* bv = (const float*)d_in[9];
  const float* Wo = (const float*)d_in[10];
  const float* bo = (const float*)d_in[11];

  char* ws = (char*)d_ws;
  size_t off = 0;
  auto take = [&](size_t bytes) {
    char* p = ws + off;
    off += (bytes + 255) & ~(size_t)255;
    return p;
  };
  const size_t WE = (size_t)DD * DD;       // 1,048,576
  const size_t TE = (size_t)BB * SS * DD;  // 4,194,304

  short* Wqh = (short*)take(WE * 2);
  short* Wql = (short*)take(WE * 2);
  short* Wkh = (short*)take(WE * 2);
  short* Wkl = (short*)take(WE * 2);
  short* Wvh = (short*)take(WE * 2);
  short* Woh = (short*)take(WE * 2);
  short* Wol = (short*)take(WE * 2);
  short* qH = (short*)take(TE * 2);
  short* qL = (short*)take(TE * 2);
  short* kH = (short*)take(TE * 2);
  short* kL = (short*)take(TE * 2);
  short* Qh = (short*)take(TE * 2);
  short* Kh = (short*)take(TE * 2);
  short* Kl = (short*)take(TE * 2);
  (void)ws_size;  // 70 MB peak (aliased below)
  // aliases (lifetimes disjoint on the serial stream):
  short* vH = qH;  // v cast, after gemm_qk consumed qH
  short* Vt = qL;  // V-proj out, after gemm_qk consumed qL
  short* aH = kH;  // attn out hi, after gemm_qk consumed kH
  short* aL = kL;  // attn out lo

  // merged elementwise pre-pass (weights + q/k splits)
  prep<<<12288, 256, 0, stream>>>(Wq, Wqh, Wql, Wk, Wkh, Wkl, Wo, Woh, Wol,
                                  Wv, Wvh, q, qH, qL, k, kH, kL);

  // merged Q+K projection (1024 blocks -> 3 blocks/CU)
  gemm_qk<<<1024, 256, 0, stream>>>(qH, qL, Wqh, Wql, bq, Qh,
                                    kH, kL, Wkh, Wkl, bk, Kh, Kl);

  // V projection (v cast must wait for gemm_qk: vH aliases qH)
  cast_rne<<<4096, 256, 0, stream>>>(v, vH);
  gemm_tile<0, 1><<<512, 256, 0, stream>>>(vH, nullptr, Wvh, nullptr, bv, Vt, nullptr);

  // attention (R6 geometry + swapped-QK packed-P softmax + MFMA row-sums)
  mha_attn<<<512, 256, 0, stream>>>(Qh, Kh, Kl, Vt, mask, aH, aL);

  // output projection
  gemm_tile<1, 2><<<512, 256, 0, stream>>>(aH, aL, Woh, Wol, bo, d_out, nullptr);
}

// Round 6
// 312.633 us; speedup vs baseline: 1.3365x; 1.0186x over previous
//
#include <hip/hip_runtime.h>

// MHA fused: B=2, S=2048, D=1024, H=16, DK=64.
// Round 12:
//  - R11 kept (attn 92.5us): swapped-QK, cvt_pk P, mask-in-exp, MFMA row-sum.
//  - attn staging rebuilt as T3-minimum 2-phase + T2 both-sides swizzle:
//    * K/Kl/V staged via global_load_lds (6x16B/thread), double-buffered,
//      ONE __syncthreads per tile (32 barriers, was 64); loads stay in
//      flight across the compute phase (drained by the barrier's vmcnt(0)).
//    * LDS rows are LINEAR 128B (gld_lds needs lane-contiguous dest); bank
//      conflicts avoided by PRE-SWIZZLING the producers (guide rule #21):
//      gemm_qk K-epilogue stores dk^((s&7)<<3); V-proj epilogue stores
//      s^((dk&7)<<3). attn reads XOR the 16B-chunk offset. Bijective within
//      64-row/64-col tiles; reads land <=2-way (free).
//    * reg-prefetch round-trip deleted (-24 VGPR, no staging ds_writes).

constexpr int BB = 2;
constexpr int SS = 2048;
constexpr int DD = 1024;
constexpr int HH = 16;
constexpr int DKK = 64;

typedef float f32x4 __attribute__((ext_vector_type(4)));
typedef __bf16 bf16x8 __attribute__((ext_vector_type(8)));
typedef short s16x8 __attribute__((ext_vector_type(8)));
typedef short s16x4 __attribute__((ext_vector_type(4)));

#define DEV static __device__ __forceinline__

DEV f32x4 mfma16(s16x8 a, s16x8 b, f32x4 c) {
  return __builtin_amdgcn_mfma_f32_16x16x32_bf16(
      __builtin_bit_cast(bf16x8, a), __builtin_bit_cast(bf16x8, b), c, 0, 0, 0);
}

DEV void split1(float x, short& h, short& l) {  // x ~= hi + lo (both bf16)
  unsigned u = __float_as_uint(x);
  h = (short)(u >> 16);
  float hf = __uint_as_float(u & 0xffff0000u);
  l = (short)(__float_as_uint(x - hf) >> 16);
}
DEV short f2bf_rne(float x) {  // round-to-nearest-even bf16
  unsigned u = __float_as_uint(x);
  return (short)((u + 0x7fffu + ((u >> 16) & 1u)) >> 16);
}
DEV unsigned cvtpk(float lo, float hi) {  // packs 2 f32 -> 2 bf16 (RNE)
  unsigned r;
  asm("v_cvt_pk_bf16_f32 %0, %1, %2" : "=v"(r) : "v"(lo), "v"(hi));
  return r;
}
DEV s16x8 load8s(const short* p) { return *(const s16x8*)p; }

DEV void gld_lds16(const short* g, short* l) {
  __builtin_amdgcn_global_load_lds(
      (const __attribute__((address_space(1))) void*)g,
      (__attribute__((address_space(3))) void*)l, 16, 0, 0);
}

// ---------------------------------------------------------------- elementwise
DEV void split4(const float* __restrict__ X, short* __restrict__ H,
                short* __restrict__ L, int i) {
  float4 x = *(const float4*)(X + i);
  float xs[4] = {x.x, x.y, x.z, x.w};
  s16x4 h4, l4;
#pragma unroll
  for (int e = 0; e < 4; ++e) {
    short h, l;
    split1(xs[e], h, l);
    h4[e] = h;
    l4[e] = l;
  }
  *(s16x4*)(H + i) = h4;
  *(s16x4*)(L + i) = l4;
}

DEV void cast4(const float* __restrict__ X, short* __restrict__ Y, int i) {
  float4 x = *(const float4*)(X + i);
  float xs[4] = {x.x, x.y, x.z, x.w};
  s16x4 y4;
#pragma unroll
  for (int e = 0; e < 4; ++e) y4[e] = f2bf_rne(xs[e]);
  *(s16x4*)(Y + i) = y4;
}

// merged elementwise pre-pass:
// blocks [0,1024) Wq split | [1024,2048) Wk split | [2048,3072) Wo split |
// [3072,4096) Wv cast | [4096,8192) q split | [8192,12288) k split.
// (v cast NOT here: vH aliases qH, which gemm_qk still reads.)
__global__ __launch_bounds__(256) void prep(
    const float* __restrict__ Wq, short* __restrict__ Wqh, short* __restrict__ Wql,
    const float* __restrict__ Wk, short* __restrict__ Wkh, short* __restrict__ Wkl,
    const float* __restrict__ Wo, short* __restrict__ Woh, short* __restrict__ Wol,
    const float* __restrict__ Wv, short* __restrict__ Wvh,
    const float* __restrict__ q, short* __restrict__ qH, short* __restrict__ qL,
    const float* __restrict__ k, short* __restrict__ kH, short* __restrict__ kL) {
  const int bid = blockIdx.x;
  const int t = threadIdx.x;
  if (bid < 4096) {
    const int w = bid >> 10;  // 0..3
    const int i = ((bid & 1023) * 256 + t) * 4;
    if (w == 0) split4(Wq, Wqh, Wql, i);
    else if (w == 1) split4(Wk, Wkh, Wkl, i);
    else if (w == 2) split4(Wo, Woh, Wol, i);
    else cast4(Wv, Wvh, i);
  } else {
    const int a = (bid - 4096) >> 12;  // 0..1
    const int i = (((bid - 4096) & 4095) * 256 + t) * 4;
    if (a == 0) split4(q, qH, qL, i);
    else split4(k, kH, kL, i);
  }
}

__global__ __launch_bounds__(256) void cast_rne(const float* __restrict__ X,
                                                short* __restrict__ Y) {
  int i = (blockIdx.x * 256 + threadIdx.x) * 4;
  cast4(X, Y, i);
}

// ---------------------------------------------------------------- merged Q+K projection
// Grid 1024: blocks 0-511 compute Q tiles (plain bf16 out, [B,H,S,DK]),
// blocks 512-1023 compute K tiles (hi/lo bf16 out, [B,H,S,DK], dk PRE-SWIZZLED
// by dk^((s&7)<<3) so attn's linear gld_lds staging + XOR read is conflict-free).
// Tile 128(M) x 64(N), BK=32, LDS double-buffered split K-loop.
__global__ __launch_bounds__(256) void gemm_qk(
    const short* __restrict__ qAh, const short* __restrict__ qAl,
    const short* __restrict__ Wqh, const short* __restrict__ Wql,
    const float* __restrict__ bq, short* __restrict__ Qo,
    const short* __restrict__ kAh, const short* __restrict__ kAl,
    const short* __restrict__ Wkh, const short* __restrict__ Wkl,
    const float* __restrict__ bk, short* __restrict__ Kho,
    short* __restrict__ Klo) {
  __shared__ short lds[2][12288];

  const int tid = threadIdx.x;
  const int lane = tid & 63, wv = tid >> 6;
  const int lo16 = lane & 15, quad = lane >> 4;
  const int sel = blockIdx.x >> 9;  // 0 = Q, 1 = K
  const int bid = blockIdx.x & 511;
  const int m0 = (bid & 31) * 128;
  const int n0 = (bid >> 5) * 64;

  const short* Agh = sel ? kAh : qAh;
  const short* Agl = sel ? kAl : qAl;
  const short* Wgh = sel ? Wkh : Wqh;
  const short* Wgl = sel ? Wkl : Wql;
  const float* bias = sel ? bk : bq;

  f32x4 acc[2][4];
#pragma unroll
  for (int mt = 0; mt < 2; ++mt)
#pragma unroll
    for (int nt = 0; nt < 4; ++nt) acc[mt][nt] = f32x4{0.f, 0.f, 0.f, 0.f};

  const int rw = tid >> 2, qw = tid & 3;
  const int ra0 = tid >> 2, ra1 = (tid + 256) >> 2;

  auto stage = [&](int k0, int buf) {
    short* sAh = lds[buf];
    short* sAl = lds[buf] + 4096;
    short* sWh = lds[buf] + 8192;
    short* sWl = lds[buf] + 10240;
    gld_lds16(Wgh + (size_t)(n0 + rw) * DD + k0 + qw * 8, sWh + tid * 8);
    gld_lds16(Wgl + (size_t)(n0 + rw) * DD + k0 + qw * 8, sWl + tid * 8);
    gld_lds16(Agh + (size_t)(m0 + ra0) * DD + k0 + qw * 8, sAh + tid * 8);
    gld_lds16(Agh + (size_t)(m0 + ra1) * DD + k0 + qw * 8, sAh + (tid + 256) * 8);
    gld_lds16(Agl + (size_t)(m0 + ra0) * DD + k0 + qw * 8, sAl + tid * 8);
    gld_lds16(Agl + (size_t)(m0 + ra1) * DD + k0 + qw * 8, sAl + (tid + 256) * 8);
  };

  stage(0, 0);

  for (int kk = 0; kk < DD / 32; ++kk) {
    __syncthreads();
    if (kk + 1 < DD / 32) stage((kk + 1) * 32, (kk + 1) & 1);

    const short* sAh = lds[kk & 1];
    const short* sAl = lds[kk & 1] + 4096;
    const short* sWh = lds[kk & 1] + 8192;
    const short* sWl = lds[kk & 1] + 10240;

    s16x8 ah[2], al[2], wh[4], wl[4];
#pragma unroll
    for (int mt = 0; mt < 2; ++mt) {
      const int r = wv * 32 + mt * 16 + lo16;
      ah[mt] = *(const s16x8*)&sAh[r * 32 + quad * 8];
      al[mt] = *(const s16x8*)&sAl[r * 32 + quad * 8];
    }
#pragma unroll
    for (int nt = 0; nt < 4; ++nt) {
      const int r = nt * 16 + lo16;
      wh[nt] = *(const s16x8*)&sWh[r * 32 + quad * 8];
      wl[nt] = *(const s16x8*)&sWl[r * 32 + quad * 8];
    }
#pragma unroll
    for (int mt = 0; mt < 2; ++mt)
#pragma unroll
      for (int nt = 0; nt < 4; ++nt) {
        acc[mt][nt] = mfma16(ah[mt], wh[nt], acc[mt][nt]);
        acc[mt][nt] = mfma16(ah[mt], wl[nt], acc[mt][nt]);
        acc[mt][nt] = mfma16(al[mt], wh[nt], acc[mt][nt]);
      }
  }

#pragma unroll
  for (int mt = 0; mt < 2; ++mt)
#pragma unroll
    for (int nt = 0; nt < 4; ++nt) {
      const int n = n0 + nt * 16 + lo16;
      const float bv = bias[n];
#pragma unroll
      for (int r = 0; r < 4; ++r) {
        const int m = m0 + wv * 32 + mt * 16 + quad * 4 + r;
        const float val = acc[mt][nt][r] + bv;
        const int b = m >> 11, s = m & 2047;
        const int h = n >> 6, dk = n & 63;
        if (sel == 0) {
          size_t idx = ((size_t)(b * HH + h) * SS + s) * DKK + dk;
          Qo[idx] = f2bf_rne(val);
        } else {
          const int dk_sw = dk ^ ((s & 7) << 3);  // pre-swizzle for attn LDS
          size_t idx = ((size_t)(b * HH + h) * SS + s) * DKK + dk_sw;
          short hh, ll;
          split1(val, hh, ll);
          Kho[idx] = hh;
          Klo[idx] = ll;
        }
      }
    }
}

// ---------------------------------------------------------------- GEMM C = A @ W^T + b
// EPI 1: plain A/W, out bf16 -> [B,H,DK,S] (V transposed, s PRE-SWIZZLED by
//        s^((dk&7)<<3) for attn's linear staging + XOR read)
// EPI 2: split A/W, out fp32 -> [4096,1024] (final output)
template <int SPLIT, int EPI>
__global__ __launch_bounds__(256) void gemm_tile(
    const short* __restrict__ Agh, const short* __restrict__ Agl,
    const short* __restrict__ Wgh, const short* __restrict__ Wgl,
    const float* __restrict__ bias, void* __restrict__ O1, void* __restrict__ O2) {
  __shared__ short lds[2][12288];

  const int tid = threadIdx.x;
  const int lane = tid & 63, wv = tid >> 6;
  const int lo16 = lane & 15, quad = lane >> 4;
  const int m0 = (blockIdx.x & 31) * 128;
  const int n0 = (blockIdx.x >> 5) * 64;

  f32x4 acc[2][4];
#pragma unroll
  for (int mt = 0; mt < 2; ++mt)
#pragma unroll
    for (int nt = 0; nt < 4; ++nt) acc[mt][nt] = f32x4{0.f, 0.f, 0.f, 0.f};

  const int rw = tid >> 2, qw = tid & 3;
  const int ra0 = tid >> 2, ra1 = (tid + 256) >> 2;

  auto stage = [&](int k0, int buf) {
    short* sAh = lds[buf];
    short* sAl = lds[buf] + 4096;
    short* sWh = lds[buf] + 8192;
    short* sWl = lds[buf] + 10240;
    gld_lds16(Wgh + (size_t)(n0 + rw) * DD + k0 + qw * 8, sWh + tid * 8);
    if constexpr (SPLIT)
      gld_lds16(Wgl + (size_t)(n0 + rw) * DD + k0 + qw * 8, sWl + tid * 8);
    gld_lds16(Agh + (size_t)(m0 + ra0) * DD + k0 + qw * 8, sAh + tid * 8);
    gld_lds16(Agh + (size_t)(m0 + ra1) * DD + k0 + qw * 8, sAh + (tid + 256) * 8);
    if constexpr (SPLIT) {
      gld_lds16(Agl + (size_t)(m0 + ra0) * DD + k0 + qw * 8, sAl + tid * 8);
      gld_lds16(Agl + (size_t)(m0 + ra1) * DD + k0 + qw * 8, sAl + (tid + 256) * 8);
    }
  };

  stage(0, 0);

  for (int kk = 0; kk < DD / 32; ++kk) {
    __syncthreads();
    if (kk + 1 < DD / 32) stage((kk + 1) * 32, (kk + 1) & 1);

    const short* sAh = lds[kk & 1];
    const short* sAl = lds[kk & 1] + 4096;
    const short* sWh = lds[kk & 1] + 8192;
    const short* sWl = lds[kk & 1] + 10240;

    s16x8 ah[2], al[2], wh[4], wl[4];
#pragma unroll
    for (int mt = 0; mt < 2; ++mt) {
      const int r = wv * 32 + mt * 16 + lo16;
      ah[mt] = *(const s16x8*)&sAh[r * 32 + quad * 8];
      if constexpr (SPLIT) al[mt] = *(const s16x8*)&sAl[r * 32 + quad * 8];
    }
#pragma unroll
    for (int nt = 0; nt < 4; ++nt) {
      const int r = nt * 16 + lo16;
      wh[nt] = *(const s16x8*)&sWh[r * 32 + quad * 8];
      if constexpr (SPLIT) wl[nt] = *(const s16x8*)&sWl[r * 32 + quad * 8];
    }
#pragma unroll
    for (int mt = 0; mt < 2; ++mt)
#pragma unroll
      for (int nt = 0; nt < 4; ++nt) {
        acc[mt][nt] = mfma16(ah[mt], wh[nt], acc[mt][nt]);
        if constexpr (SPLIT) {
          acc[mt][nt] = mfma16(ah[mt], wl[nt], acc[mt][nt]);
          acc[mt][nt] = mfma16(al[mt], wh[nt], acc[mt][nt]);
        }
      }
  }

#pragma unroll
  for (int mt = 0; mt < 2; ++mt)
#pragma unroll
    for (int nt = 0; nt < 4; ++nt) {
      const int n = n0 + nt * 16 + lo16;
      const float bv = bias[n];
#pragma unroll
      for (int r = 0; r < 4; ++r) {
        const int m = m0 + wv * 32 + mt * 16 + quad * 4 + r;
        const float val = acc[mt][nt][r] + bv;
        const int b = m >> 11, s = m & 2047;
        const int h = n >> 6, dk = n & 63;
        if constexpr (EPI == 1) {
          const int s_sw = s ^ ((dk & 7) << 3);  // pre-swizzle for attn LDS
          size_t idx = ((size_t)(b * HH + h) * DKK + dk) * SS + s_sw;
          ((short*)O1)[idx] = f2bf_rne(val);
        } else {
          ((float*)O1)[(size_t)m * DD + n] = val;
        }
      }
    }
}

// ---------------------------------------------------------------- flash attention
// Block = 128 q-rows of one head (4 waves x 32 rows), grid 512.
// K/Kl/V staged via global_load_lds (async DMA), DOUBLE-BUFFERED, linear
// 128B LDS rows; ONE barrier per 64-key tile (vmcnt drained by barrier).
// Producers pre-swizzled (dk^((s&7)<<3) / s^((dk&7)<<3)) -> reads XOR the
// 16B chunk offset -> <=2-way bank conflicts. SWAPPED QK (S[k][q]); P packed
// via v_cvt_pk_bf16_f32 + b32 stores; mask folded into exp addend; row-sum
// on MFMA pipe (sacc = mfma(pa, ones)); setprio(1) around MFMA clusters.
constexpr int PAD = 68;  // sP only
constexpr int NKB = SS / 64;  // 32
constexpr float EXPSC = 0.125f * 1.4426950408889634f;  // fold /sqrt(DK) into exp2

__global__ __launch_bounds__(256, 2) void mha_attn(
    const short* __restrict__ Qh, const short* __restrict__ Kh,
    const short* __restrict__ Kl, const short* __restrict__ Vt,
    const int* __restrict__ mask, short* __restrict__ Ah,
    short* __restrict__ Al) {
  __shared__ short sKV[2][12288];  // [Kh 4096 | Kl 4096 | V 4096] shorts, linear
  __shared__ short sP[4][32 * PAD];

  const int tid = threadIdx.x;
  const int lane = tid & 63, wv = tid >> 6;
  const int lo16 = lane & 15, quad = lane >> 4;
  const int bid = blockIdx.x;                         // 512 blocks
  const int head = (bid & 7) * 4 + ((bid >> 3) & 3);  // = b*16 + h (head->XCD pin)
  const int qblk = bid >> 5;                          // 0..15
  const int q0 = qblk * 128 + wv * 32;                // this wave's 32 q rows
  const int b = head >> 4;

  const size_t hbase = (size_t)head * SS;
  const size_t vbase = (size_t)head * DKK;

  constexpr short ONE_BF = (short)0x3F80;
  const s16x8 ones8 = {ONE_BF, ONE_BF, ONE_BF, ONE_BF,
                       ONE_BF, ONE_BF, ONE_BF, ONE_BF};

  s16x8 qh[2][2];
#pragma unroll
  for (int rt = 0; rt < 2; ++rt) {
    size_t qb = (hbase + q0 + rt * 16 + lo16) * DKK + quad * 8;
#pragma unroll
    for (int c = 0; c < 2; ++c) qh[rt][c] = load8s(Qh + qb + c * 32);
  }

  f32x4 Oacc[2][4];
#pragma unroll
  for (int rt = 0; rt < 2; ++rt)
#pragma unroll
    for (int t = 0; t < 4; ++t) Oacc[rt][t] = f32x4{0.f, 0.f, 0.f, 0.f};
  f32x4 sacc[2];  // row-sums via MFMA vs ones
  sacc[0] = f32x4{0.f, 0.f, 0.f, 0.f};
  sacc[1] = f32x4{0.f, 0.f, 0.f, 0.f};

  // async staging: thread handles 2 chunks per buffer (512 chunks of 16B each)
  auto STAGE = [&](int k0, int buf) {
    short* base = &sKV[buf][0];
#pragma unroll
    for (int i = 0; i < 2; ++i) {
      const int ch = tid + 256 * i;     // 0..511
      const int row = ch >> 3;          // 0..63
      const int inner = (ch & 7) * 8;   // shorts
      gld_lds16(Kh + (hbase + k0 + row) * DKK + inner, base + ch * 8);
      gld_lds16(Kl + (hbase + k0 + row) * DKK + inner, base + 4096 + ch * 8);
      gld_lds16(Vt + (vbase + row) * SS + k0 + inner, base + 8192 + ch * 8);
    }
  };

  STAGE(0, 0);

  for (int kb = 0; kb < NKB; ++kb) {
    const int k0g = kb * 64;
    const int cur = kb & 1;
    __syncthreads();  // drains vmcnt -> sKV[cur] ready; prev reads done

    if (kb + 1 < NKB) STAGE(k0g + 64, cur ^ 1);  // async, lands before next barrier

    const short* sKh = &sKV[cur][0];
    const short* sKl = &sKV[cur][4096];
    const short* sV = &sKV[cur][8192];

    // mask -> exp addend: 0 (keep) or -32768 (exp2 underflows to exact 0)
    float addf[4][4];
#pragma unroll
    for (int sub = 0; sub < 4; ++sub) {
      const int4 mq = *(const int4*)(mask + b * SS + k0g + sub * 16 + quad * 4);
      addf[sub][0] = mq.x ? 0.f : -32768.f;
      addf[sub][1] = mq.y ? 0.f : -32768.f;
      addf[sub][2] = mq.z ? 0.f : -32768.f;
      addf[sub][3] = mq.w ? 0.f : -32768.f;
    }

    // ---- QK^T (swapped): sc4[rt][sub][r] = S[k=sub*16+quad*4+r][q=q0+rt*16+lo16]
    f32x4 sc4[2][4];
    __builtin_amdgcn_s_setprio(1);
#pragma unroll
    for (int sub = 0; sub < 4; ++sub) {
      sc4[0][sub] = f32x4{0.f, 0.f, 0.f, 0.f};
      sc4[1][sub] = f32x4{0.f, 0.f, 0.f, 0.f};
      const int krow = sub * 16 + lo16;
      const int ksw = (krow & 7) << 3;
#pragma unroll
      for (int c = 0; c < 2; ++c) {
        const int koff = krow * 64 + ((c * 32 + quad * 8) ^ ksw);
        s16x8 kh = *(const s16x8*)&sKh[koff];
        s16x8 kl = *(const s16x8*)&sKl[koff];
#pragma unroll
        for (int rt = 0; rt < 2; ++rt) {
          sc4[rt][sub] = mfma16(kh, qh[rt][c], sc4[rt][sub]);
          sc4[rt][sub] = mfma16(kl, qh[rt][c], sc4[rt][sub]);
        }
      }
    }
    __builtin_amdgcn_s_setprio(0);

    // ---- softmax (no-max): p = exp2(fma(s, c, addend)), pack, b32 stores
#pragma unroll
    for (int rt = 0; rt < 2; ++rt) {
      const int prow = (rt * 16 + lo16) * PAD;
#pragma unroll
      for (int sub = 0; sub < 4; ++sub) {
        const float p0 = exp2f(fmaf(sc4[rt][sub][0], EXPSC, addf[sub][0]));
        const float p1 = exp2f(fmaf(sc4[rt][sub][1], EXPSC, addf[sub][1]));
        const float p2 = exp2f(fmaf(sc4[rt][sub][2], EXPSC, addf[sub][2]));
        const float p3 = exp2f(fmaf(sc4[rt][sub][3], EXPSC, addf[sub][3]));
        *(unsigned*)&sP[wv][prow + sub * 16 + quad * 4] = cvtpk(p0, p1);
        *(unsigned*)&sP[wv][prow + sub * 16 + quad * 4 + 2] = cvtpk(p2, p3);
      }
    }

    // ---- row-sum (MFMA vs ones) + PV
    s16x8 pa[2][2];
#pragma unroll
    for (int rt = 0; rt < 2; ++rt)
#pragma unroll
      for (int c = 0; c < 2; ++c)
        pa[rt][c] = *(const s16x8*)&sP[wv][(rt * 16 + lo16) * PAD + c * 32 + quad * 8];
    __builtin_amdgcn_s_setprio(1);
#pragma unroll
    for (int rt = 0; rt < 2; ++rt) {
      sacc[rt] = mfma16(pa[rt][0], ones8, sacc[rt]);
      sacc[rt] = mfma16(pa[rt][1], ones8, sacc[rt]);
    }
#pragma unroll
    for (int t = 0; t < 4; ++t) {
      const int vrow = t * 16 + lo16;
      const int vsw = (vrow & 7) << 3;
#pragma unroll
      for (int c = 0; c < 2; ++c) {
        s16x8 vb = *(const s16x8*)&sV[vrow * 64 + ((c * 32 + quad * 8) ^ vsw)];
#pragma unroll
        for (int rt = 0; rt < 2; ++rt)
          Oacc[rt][t] = mfma16(pa[rt][c], vb, Oacc[rt][t]);
      }
    }
    __builtin_amdgcn_s_setprio(0);
    // no second barrier: next iteration's barrier covers both hazards
  }

  const int h = head & 15;
#pragma unroll
  for (int rt = 0; rt < 2; ++rt) {
#pragma unroll
    for (int r = 0; r < 4; ++r) {
      const float rinv = 1.0f / sacc[rt][r];
#pragma unroll
      for (int t = 0; t < 4; ++t) {
        const float val = Oacc[rt][t][r] * rinv;
        const int row = q0 + rt * 16 + quad * 4 + r;
        const int col = h * DKK + t * 16 + lo16;
        const size_t idx = ((size_t)b * SS + row) * DD + col;
        short hh, ll;
        split1(val, hh, ll);
        Ah[idx] = hh;
        Al[idx] = ll;
      }
    }
  }
}

// ---------------------------------------------------------------- launch
extern "C" void kernel_launch(void* const* d_in, const int* in_sizes, int n_in,
                              void* d_out, int out_size, void* d_ws, size_t ws_size,
                              hipStream_t stream) {
  const float* q = (const float*)d_in[0];
  const float* k = (const float*)d_in[1];
  const float* v = (const float*)d_in[2];
  const int* mask = (const int*)d_in[3];
  const float* Wq = (const float*)d_in[4];
  const float* bq = (const float*)d_in[5];
  const float* Wk = (const float*)d_in[6];
  const float* bk = (const float*)d_in[7];
  const float* Wv = (const float*)d_in[8];
  const float* bv = (const float*)d_in[9];
  const float* Wo = (const float*)d_in[10];
  const float* bo = (const float*)d_in[11];

  char* ws = (char*)d_ws;
  size_t off = 0;
  auto take = [&](size_t bytes) {
    char* p = ws + off;
    off += (bytes + 255) & ~(size_t)255;
    return p;
  };
  const size_t WE = (size_t)DD * DD;       // 1,048,576
  const size_t TE = (size_t)BB * SS * DD;  // 4,194,304

  short* Wqh = (short*)take(WE * 2);
  short* Wql = (short*)take(WE * 2);
  short* Wkh = (short*)take(WE * 2);
  short* Wkl = (short*)take(WE * 2);
  short* Wvh = (short*)take(WE * 2);
  short* Woh = (short*)take(WE * 2);
  short* Wol = (short*)take(WE * 2);
  short* qH = (short*)take(TE * 2);
  short* qL = (short*)take(TE * 2);
  short* kH = (short*)take(TE * 2);
  short* kL = (short*)take(TE * 2);
  short* Qh = (short*)take(TE * 2);
  short* Kh = (short*)take(TE * 2);
  short* Kl = (short*)take(TE * 2);
  (void)ws_size;  // 70 MB peak (aliased below)
  // aliases (lifetimes disjoint on the serial stream):
  short* vH = qH;  // v cast, after gemm_qk consumed qH
  short* Vt = qL;  // V-proj out, after gemm_qk consumed qL
  short* aH = kH;  // attn out hi, after gemm_qk consumed kH
  short* aL = kL;  // attn out lo

  // merged elementwise pre-pass (weights + q/k splits)
  prep<<<12288, 256, 0, stream>>>(Wq, Wqh, Wql, Wk, Wkh, Wkl, Wo, Woh, Wol,
                                  Wv, Wvh, q, qH, qL, k, kH, kL);

  // merged Q+K projection (1024 blocks -> 3 blocks/CU)
  gemm_qk<<<1024, 256, 0, stream>>>(qH, qL, Wqh, Wql, bq, Qh,
                                    kH, kL, Wkh, Wkl, bk, Kh, Kl);

  // V projection (v cast must wait for gemm_qk: vH aliases qH)
  cast_rne<<<4096, 256, 0, stream>>>(v, vH);
  gemm_tile<0, 1><<<512, 256, 0, stream>>>(vH, nullptr, Wvh, nullptr, bv, Vt, nullptr);

  // attention (2-phase gld_lds staging, swizzled producers, 1 barrier/tile)
  mha_attn<<<512, 256, 0, stream>>>(Qh, Kh, Kl, Vt, mask, aH, aL);

  // output projection
  gemm_tile<1, 2><<<512, 256, 0, stream>>>(aH, aL, Woh, Wol, bo, d_out, nullptr);
}